// Round 15
// baseline (510.950 us; speedup 1.0000x reference)
//
#include <hip/hip_runtime.h>
#include <cstdio>

#define Nn 50000
#define Ee 800000
#define Ff 512
#define Dd 256
#define Gg 8
#define SCANB 49   // ceil(Nn/1024)

typedef short short8 __attribute__((ext_vector_type(8)));
typedef __bf16 bf16x8 __attribute__((ext_vector_type(8)));
typedef float f32x4 __attribute__((ext_vector_type(4)));
typedef _Float16 half2v __attribute__((ext_vector_type(2)));

#if defined(__has_builtin)
#if __has_builtin(__builtin_amdgcn_cvt_f32_fp8)
#define HAS_CVTFP8 1
#endif
#endif

__device__ inline unsigned short f2bf(float f) {
  unsigned u = __float_as_uint(f);
  u += 0x7FFFu + ((u >> 16) & 1u);
  return (unsigned short)(u >> 16);
}
__device__ inline float bf2f(unsigned short h) {
  return __uint_as_float(((unsigned)h) << 16);
}

// OCP e4m3 encode (RNE, clamp to +-448, denormals handled)
__device__ inline unsigned char f2fp8(float f) {
  const float af = fabsf(f);
  const unsigned s = (f < 0.f) ? 0x80u : 0u;
  if (af >= 448.f) return (unsigned char)(s | 0x7E);
  if (af < 0.015625f) {
    int q = (int)(af * 512.f + 0.5f);
    return (unsigned char)(s | q);
  }
  unsigned u = __float_as_uint(af);
  unsigned m = u & 0x7fffffu;
  unsigned e = u >> 23;
  unsigned r = m + 0x7ffffu + ((m >> 20) & 1u);
  if (r >> 23) { e += 1; r = 0; }
  unsigned em = ((e - 120u) << 3) | ((r >> 20) & 7u);
  if (em > 0x7Eu) em = 0x7Eu;
  return (unsigned char)(s | em);
}

// OCP e4m3 decode, byte SEL of a dword (compile-time constant)
template <int SEL>
__device__ inline float fp8tof(unsigned v) {
#ifdef HAS_CVTFP8
  return __builtin_amdgcn_cvt_f32_fp8(v, SEL);
#else
  unsigned b = (v >> (SEL * 8)) & 0xffu;
  unsigned em = b & 0x7fu;
  float n = __uint_as_float((em << 20) + 0x3C000000u);
  float dn = (float)em * 0.001953125f;
  float r = (em < 8u) ? dn : n;
  return (b & 0x80u) ? -r : r;
#endif
}

__device__ inline void gload16(const void* g, void* l) {
  __builtin_amdgcn_global_load_lds((const __attribute__((address_space(1))) void*)g,
                                   (__attribute__((address_space(3))) void*)l, 16, 0, 0);
}

// ---------------- CSR build (rank-based: one atomic pass) ----------------

__global__ void hist_kernel(const int* __restrict__ dst, int* __restrict__ deg,
                            int* __restrict__ rank) {
  int i = blockIdx.x * blockDim.x + threadIdx.x;
  int stride = gridDim.x * blockDim.x;
  for (; i < Ee; i += stride) rank[i] = atomicAdd(&deg[dst[i]], 1);
}

__global__ __launch_bounds__(1024) void scan1_kernel(const int* __restrict__ deg,
                                                     int* __restrict__ off,
                                                     int* __restrict__ bsum) {
  __shared__ int wsum[16];
  int tid = threadIdx.x, lane = tid & 63, w = tid >> 6;
  int i = blockIdx.x * 1024 + tid;
  int v = (i < Nn) ? deg[i] : 0;
  int x = v;
#pragma unroll
  for (int o = 1; o < 64; o <<= 1) {
    int t = __shfl_up(x, o);
    if (lane >= o) x += t;
  }
  if (lane == 63) wsum[w] = x;
  __syncthreads();
  if (w == 0 && lane < 16) {
    int y = wsum[lane];
#pragma unroll
    for (int o = 1; o < 16; o <<= 1) {
      int t = __shfl_up(y, o);
      if (lane >= o) y += t;
    }
    wsum[lane] = y;
  }
  __syncthreads();
  int incl = x + (w ? wsum[w - 1] : 0);
  if (i < Nn) off[i] = incl - v;
  if (tid == 1023) bsum[blockIdx.x] = incl;
}

__global__ void scan2_kernel(const int* __restrict__ bsum, int* __restrict__ boff,
                             int* __restrict__ offN) {
  int lane = threadIdx.x;
  int v = (lane < SCANB) ? bsum[lane] : 0;
  int x = v;
#pragma unroll
  for (int o = 1; o < 64; o <<= 1) {
    int t = __shfl_up(x, o);
    if (lane >= o) x += t;
  }
  if (lane < SCANB) boff[lane] = x - v;
  if (lane == 63) *offN = x;
}

__global__ void scan3_kernel(int* __restrict__ off, const int* __restrict__ boff) {
  int i = blockIdx.x * 256 + threadIdx.x;
  if (i < Nn) off[i] += boff[i >> 10];
}

__global__ void scatter_kernel(const int* __restrict__ src, const int* __restrict__ dst,
                               const int* __restrict__ off, const int* __restrict__ rank,
                               int* __restrict__ ssrc) {
  int i = blockIdx.x * blockDim.x + threadIdx.x;
  int stride = gridDim.x * blockDim.x;
  for (; i < Ee; i += stride) {
    ssrc[off[dst[i]] + rank[i]] = src[i];
  }
}

// ---------------- conversions ----------------

__global__ void round_kernel(const float* __restrict__ in, unsigned short* __restrict__ out,
                             int M, int K) {
  const int kg4 = K >> 2;
  int i = blockIdx.x * blockDim.x + threadIdx.x;
  const int total = M * kg4;
  const int stride = gridDim.x * blockDim.x;
  for (; i < total; i += stride) {
    const int row = i / kg4, kg = i - row * kg4;
    const float4 v = *(const float4*)(in + (size_t)row * K + kg * 4);
    ushort4 h;
    h.x = f2bf(v.x); h.y = f2bf(v.y); h.z = f2bf(v.z); h.w = f2bf(v.w);
    *(ushort4*)(out + (size_t)row * K + kg * 4) = h;
  }
}

// 4x W [K][256] fp32 -> B [1024][K] bf16 hi-only, transposed; row n = z*256+c
__global__ void convw_kernel(const float* __restrict__ W0, const float* __restrict__ W1,
                             const float* __restrict__ W2, const float* __restrict__ W3,
                             unsigned short* __restrict__ B, int K) {
  int i = blockIdx.x * blockDim.x + threadIdx.x;
  const int total = 1024 * K;
  const int stride = gridDim.x * blockDim.x;
  for (; i < total; i += stride) {
    const int n = i & 1023;
    const int k = i >> 10;
    const int z = n >> 8, c = n & 255;
    const float* W = z == 0 ? W0 : z == 1 ? W1 : z == 2 ? W2 : W3;
    B[(size_t)n * K + k] = f2bf(W[(size_t)k * Dd + c]);
  }
}

// ---------------- shared K-loop for both GEMM kernels (128x128 tile) ----------------
// Stages A[bm..bm+128) x 64 and B rows [brow..brow+128) x 64 per step, accumulates.

__device__ __forceinline__ void gemm_kloop(
    const unsigned short* __restrict__ A2, int M, int K,
    const unsigned short* __restrict__ B, int brow, int bm,
    unsigned short* As, unsigned short* Bs, int lane, int w, int wr, int wc,
    f32x4 (&acc)[4][4]) {
  const int nsteps = K >> 6;
  const int srow = lane >> 3, sslot = lane & 7;
  const int fr = lane & 15, fq = lane >> 4;
  for (int s = 0; s < nsteps; ++s) {
    const int kk = s << 6;
    __syncthreads();
#pragma unroll
    for (int h = 0; h < 4; ++h) {
      const int q = h * 4 + w;
      const int r = q * 8 + srow;
      const int g = sslot ^ (r & 7);
      int ga = bm + r; if (ga > M - 1) ga = M - 1;
      gload16(A2 + (size_t)ga * K + kk + g * 8, (char*)As + q * 1024);
      gload16(B + (size_t)(brow + r) * K + kk + g * 8, (char*)Bs + q * 1024);
    }
    __syncthreads();
    short8 av[2][4], bv[2][4];
#pragma unroll
    for (int kh = 0; kh < 2; ++kh)
#pragma unroll
      for (int i = 0; i < 4; ++i) {
        const int ra = wr * 64 + i * 16 + fr;
        av[kh][i] = *(const short8*)((const char*)As + ra * 128 + (((kh * 4 + fq) ^ (ra & 7)) << 4));
        const int rb = wc * 64 + i * 16 + fr;
        bv[kh][i] = *(const short8*)((const char*)Bs + rb * 128 + (((kh * 4 + fq) ^ (rb & 7)) << 4));
      }
#pragma unroll
    for (int kh = 0; kh < 2; ++kh)
#pragma unroll
      for (int mi = 0; mi < 4; ++mi)
#pragma unroll
        for (int ni = 0; ni < 4; ++ni)
          acc[mi][ni] = __builtin_amdgcn_mfma_f32_16x16x32_bf16(
              __builtin_bit_cast(bf16x8, av[kh][mi]),
              __builtin_bit_cast(bf16x8, bv[kh][ni]), acc[mi][ni], 0, 0, 0);
  }
}

// ---- q/s GEMM: fp16 out. grid 1568 = 8 xcd * 49 rowtiles * 4 cg (q0,q1,s0,s1) ----
__global__ __launch_bounds__(256)
void gemm_qs(const unsigned short* __restrict__ A2, int M, int K,
             const unsigned short* __restrict__ B,
             const float* __restrict__ bq, const float* __restrict__ bs,
             _Float16* __restrict__ qout, _Float16* __restrict__ sout) {
  __shared__ __align__(16) char smem[32768];
  unsigned short* As = (unsigned short*)smem;
  unsigned short* Bs = (unsigned short*)(smem + 16384);
  const int tid = threadIdx.x;
  const int lane = tid & 63, w = tid >> 6;
  const int wr = w >> 1, wc = w & 1;
  const int p = blockIdx.x;
  const int i2 = p >> 3;
  const int bm = ((p & 7) * 49 + (i2 >> 2)) * 128;
  const int cg = i2 & 3;
  const int isS = cg >> 1;
  const int colbase = (cg & 1) * 128;
  const int brow = (isS ? 768 : 0) + colbase;
  const int fr = lane & 15, fq = lane >> 4;

  f32x4 acc[4][4] = {};
  gemm_kloop(A2, M, K, B, brow, bm, As, Bs, lane, w, wr, wc, acc);

  const float* bp = isS ? bs : bq;
  _Float16* out = isS ? sout : qout;
  __syncthreads();
#pragma unroll
  for (int mi = 0; mi < 4; ++mi)
#pragma unroll
    for (int ni = 0; ni < 4; ++ni) {
      const int col = wc * 64 + ni * 16 + fr;
      const float bias = bp[colbase + col];
#pragma unroll
      for (int j = 0; j < 4; ++j) {
        const int row = wr * 64 + mi * 16 + fq * 4 + j;
        *(_Float16*)(smem + row * 256 + ((col * 2) ^ ((row & 7) << 4))) =
            (_Float16)(acc[mi][ni][j] + bias);
      }
    }
  __syncthreads();
  const int row = tid >> 1, half = tid & 1;
  const int grow = bm + row;
  if (grow < M) {
    const int sh = (row & 7) << 4;
    uint4* dstp = (uint4*)((char*)out + (size_t)grow * 512 + colbase * 2 + half * 128);
#pragma unroll
    for (int k = 0; k < 8; ++k)
      dstp[k] = *(const uint4*)(smem + row * 256 + ((half * 128 + k * 16) ^ sh));
  }
}

// ---- k/v GEMM: fp8 out into kv rows (512B: K [0,256), V [256,512)) ----
__global__ __launch_bounds__(256)
void gemm_kv(const unsigned short* __restrict__ A2, int M, int K,
             const unsigned short* __restrict__ B,
             const float* __restrict__ bk, const float* __restrict__ bv,
             unsigned char* __restrict__ kvout) {
  __shared__ __align__(16) char smem[32768];
  unsigned short* As = (unsigned short*)smem;
  unsigned short* Bs = (unsigned short*)(smem + 16384);
  const int tid = threadIdx.x;
  const int lane = tid & 63, w = tid >> 6;
  const int wr = w >> 1, wc = w & 1;
  const int p = blockIdx.x;
  const int i2 = p >> 3;
  const int bm = ((p & 7) * 49 + (i2 >> 2)) * 128;
  const int cg = i2 & 3;
  const int isV = cg >> 1;
  const int colbase = (cg & 1) * 128;
  const int brow = 256 + isV * 256 + colbase;      // B rows: k=256.., v=512..
  const int fr = lane & 15, fq = lane >> 4;

  f32x4 acc[4][4] = {};
  gemm_kloop(A2, M, K, B, brow, bm, As, Bs, lane, w, wr, wc, acc);

  const float* bp = isV ? bv : bk;
  const int obase = isV * 256 + colbase;           // byte offset in 512B kv row
  unsigned char* S8 = (unsigned char*)smem;
  __syncthreads();
#pragma unroll
  for (int mi = 0; mi < 4; ++mi)
#pragma unroll
    for (int ni = 0; ni < 4; ++ni) {
      const int col = wc * 64 + ni * 16 + fr;
      const float bias = bp[colbase + col];
#pragma unroll
      for (int j = 0; j < 4; ++j) {
        const int row = wr * 64 + mi * 16 + fq * 4 + j;
        S8[row * 128 + (col ^ ((row & 7) << 4))] = f2fp8(acc[mi][ni][j] + bias);
      }
    }
  __syncthreads();
  const int row = tid >> 1, half = tid & 1;
  const int grow = bm + row;
  if (grow < M) {
    const int sh = (row & 7) << 4;
    uint4* dstp = (uint4*)(kvout + (size_t)grow * 512 + obase + half * 64);
#pragma unroll
    for (int k = 0; k < 4; ++k)
      dstp[k] = *(const uint4*)(smem + row * 128 + ((half * 64 + k * 16) ^ sh));
  }
}

// ---------------- per-node attention (one wave per dst node, online softmax) ----------------
// q: fp16 [Nn][256]; kv row 512B: K fp8 [0,256), V fp8 [256,512); s fp16 [Nn][256].

__global__ __launch_bounds__(256)
void attn_kernel(const _Float16* __restrict__ qbuf, const unsigned char* __restrict__ kvb,
                 const _Float16* __restrict__ sbuf, const int* __restrict__ off,
                 const int* __restrict__ ssrc, unsigned short* __restrict__ hbout) {
  int gw = (int)((blockIdx.x * 256 + threadIdx.x) >> 6);
  if (gw >= Nn) return;
  int lane = threadIdx.x & 63;

  const uint2 qv = *(const uint2*)(qbuf + (size_t)gw * Dd + lane * 4);
  const half2v q01 = __builtin_bit_cast(half2v, qv.x);
  const half2v q23 = __builtin_bit_cast(half2v, qv.y);
  const float qx = (float)q01[0], qy = (float)q01[1];
  const float qz = (float)q23[0], qw = (float)q23[1];
  int e0 = off[gw], e1 = off[gw + 1];
  const float scale = 0.08838834764831845f;

  float m = -3.4e38f, d = 0.f;
  float ax = 0.f, ay = 0.f, az = 0.f, aw = 0.f;

  for (int e = e0; e < e1; e += 8) {
    int sx[8];
#pragma unroll
    for (int t = 0; t < 8; ++t) {
      const int ee = e + t;
      sx[t] = ssrc[ee < e1 ? ee : e1 - 1];
    }
    unsigned kw[8], vw[8];
#pragma unroll
    for (int t = 0; t < 8; ++t) {
      const unsigned char* row = kvb + (size_t)sx[t] * 512;
      kw[t] = *(const unsigned*)(row + lane * 4);
      vw[t] = *(const unsigned*)(row + 256 + lane * 4);
    }
    float p[8];
#pragma unroll
    for (int t = 0; t < 8; ++t) {
      float pp = qx * fp8tof<0>(kw[t]);
      pp = fmaf(qy, fp8tof<1>(kw[t]), pp);
      pp = fmaf(qz, fp8tof<2>(kw[t]), pp);
      pp = fmaf(qw, fp8tof<3>(kw[t]), pp);
      p[t] = pp;
    }
#pragma unroll
    for (int o = 16; o >= 1; o >>= 1)
#pragma unroll
      for (int t = 0; t < 8; ++t) p[t] += __shfl_xor(p[t], o);
    float sc[8];
#pragma unroll
    for (int t = 0; t < 8; ++t)
      sc[t] = (e + t < e1) ? p[t] * scale : -3.0e38f;
    float mx = m;
#pragma unroll
    for (int t = 0; t < 8; ++t) mx = fmaxf(mx, sc[t]);
    const float f = __expf(m - mx);
    float wsum = 0.f, vx = 0.f, vy = 0.f, vz = 0.f, vww = 0.f;
#pragma unroll
    for (int t = 0; t < 8; ++t) {
      const float wt = __expf(sc[t] - mx);
      wsum += wt;
      vx = fmaf(wt, fp8tof<0>(vw[t]), vx);
      vy = fmaf(wt, fp8tof<1>(vw[t]), vy);
      vz = fmaf(wt, fp8tof<2>(vw[t]), vz);
      vww = fmaf(wt, fp8tof<3>(vw[t]), vww);
    }
    d = d * f + wsum;
    ax = ax * f + vx;
    ay = ay * f + vy;
    az = az * f + vz;
    aw = aw * f + vww;
    m = mx;
  }

  float inv = 1.f / (d + 1e-16f);
  const uint2 sv = *(const uint2*)(sbuf + (size_t)gw * Dd + lane * 4);
  const half2v s01 = __builtin_bit_cast(half2v, sv.x);
  const half2v s23 = __builtin_bit_cast(half2v, sv.y);
  ushort4 hh;
  hh.x = f2bf(fmaxf(fmaf(ax, inv, (float)s01[0]), 0.f));
  hh.y = f2bf(fmaxf(fmaf(ay, inv, (float)s01[1]), 0.f));
  hh.z = f2bf(fmaxf(fmaf(az, inv, (float)s23[0]), 0.f));
  hh.w = f2bf(fmaxf(fmaf(aw, inv, (float)s23[1]), 0.f));
  *(ushort4*)(hbout + (size_t)gw * Dd + lane * 4) = hh;
}

// ---------------- pooling (bf16 input) + fc ----------------

__global__ __launch_bounds__(256)
void pool_kernel(const unsigned short* __restrict__ h, const int* __restrict__ batch,
                 float* __restrict__ pooled) {
  int c = threadIdx.x;
  int n0 = blockIdx.x * 128;
  int n1 = min(n0 + 128, Nn);
  int curg = batch[n0];
  float mx = 0.f;
  for (int n = n0; n < n1; ++n) {
    int g = batch[n];
    if (g != curg) {
      atomicMax((int*)(pooled + curg * Dd + c), __float_as_int(mx));
      mx = 0.f;
      curg = g;
    }
    mx = fmaxf(mx, bf2f(h[(size_t)n * Dd + c]));
  }
  atomicMax((int*)(pooled + curg * Dd + c), __float_as_int(mx));
}

__global__ __launch_bounds__(512)
void fc_kernel(const float* __restrict__ pooled,
               const float* __restrict__ wf1, const float* __restrict__ bf1,
               const float* __restrict__ wf2, const float* __restrict__ bf2,
               float* __restrict__ outp) {
  __shared__ float t[Gg][64];
  int tid = threadIdx.x;
  int g = tid >> 6, j = tid & 63;
  float acc = bf1[j];
  for (int c = 0; c < Dd; ++c) acc = fmaf(pooled[g * Dd + c], wf1[c * 64 + j], acc);
  t[g][j] = acc;
  __syncthreads();
  if (tid < Gg * 4) {
    int gg = tid >> 2, cc = tid & 3;
    float a2 = bf2[cc];
    for (int j2 = 0; j2 < 64; ++j2) a2 = fmaf(t[gg][j2], wf2[j2 * 4 + cc], a2);
    outp[gg * 4 + cc] = a2;
  }
}

// ---------------- host ----------------

extern "C" void kernel_launch(void* const* d_in, const int* in_sizes, int n_in,
                              void* d_out, int out_size, void* d_ws, size_t ws_size,
                              hipStream_t stream) {
  const float* x   = (const float*)d_in[0];
  const int* ei    = (const int*)d_in[1];
  const int* srcE  = ei;
  const int* dstE  = ei + Ee;
  const int* batch = (const int*)d_in[2];
  const float* wq1 = (const float*)d_in[3];  const float* bq1 = (const float*)d_in[4];
  const float* wk1 = (const float*)d_in[5];  const float* bk1 = (const float*)d_in[6];
  const float* wv1 = (const float*)d_in[7];  const float* bv1 = (const float*)d_in[8];
  const float* ws1 = (const float*)d_in[9];  const float* bs1 = (const float*)d_in[10];
  const float* wq2 = (const float*)d_in[11]; const float* bq2 = (const float*)d_in[12];
  const float* wk2 = (const float*)d_in[13]; const float* bk2 = (const float*)d_in[14];
  const float* wv2 = (const float*)d_in[15]; const float* bv2 = (const float*)d_in[16];
  const float* ws2 = (const float*)d_in[17]; const float* bs2 = (const float*)d_in[18];
  const float* wf1 = (const float*)d_in[19]; const float* bf1 = (const float*)d_in[20];
  const float* wf2 = (const float*)d_in[21]; const float* bf2 = (const float*)d_in[22];
  float* outp = (float*)d_out;
  char* ws = (char*)d_ws;

  auto al256 = [](size_t v) { return (v + 255) & ~(size_t)255; };
  size_t o_deg  = 0;
  size_t o_pool = o_deg + (size_t)Nn * 4;
  size_t zbytes = o_pool + (size_t)Gg * Dd * 4;
  size_t o_off  = al256(zbytes);
  size_t o_ssrc = al256(o_off + (size_t)(Nn + 1) * 4);
  size_t o_rank = al256(o_ssrc + (size_t)Ee * 4);
  size_t o_q    = al256(o_rank + (size_t)Ee * 4);                 // fp16 [Nn][256]
  size_t o_kv   = al256(o_q + (size_t)Nn * Dd * 2);               // 512B rows [Nn]
  size_t o_s    = al256(o_kv + (size_t)Nn * 512);                 // fp16 [Nn][256]
  size_t o_b1   = al256(o_s + (size_t)Nn * Dd * 2);               // bf16 [1024][512]
  size_t o_b2   = al256(o_b1 + (size_t)1024 * Ff * 2);            // bf16 [1024][256]
  size_t o_a    = al256(o_b2 + (size_t)1024 * Dd * 2);            // bf16 [Nn][512] x / h overlay
  size_t o_bsum = al256(o_a + (size_t)Nn * Ff * 2);
  size_t o_boff = al256(o_bsum + (size_t)SCANB * 4);
  size_t total  = o_boff + (size_t)SCANB * 4;
  if (ws_size < total) {
    fprintf(stderr, "kernel_launch: ws too small: %zu < %zu\n", ws_size, total);
    return;
  }

  int*   deg    = (int*)(ws + o_deg);
  float* pooled = (float*)(ws + o_pool);
  int*   off    = (int*)(ws + o_off);
  int*   ssrc   = (int*)(ws + o_ssrc);
  int*   rank   = (int*)(ws + o_rank);
  _Float16* qb  = (_Float16*)(ws + o_q);
  unsigned char* kvb = (unsigned char*)(ws + o_kv);
  _Float16* sb  = (_Float16*)(ws + o_s);
  unsigned short* b1 = (unsigned short*)(ws + o_b1);
  unsigned short* b2 = (unsigned short*)(ws + o_b2);
  unsigned short* a2  = (unsigned short*)(ws + o_a);    // [Nn][512] bf16 (x)
  unsigned short* hb  = (unsigned short*)(ws + o_a);    // [Nn][256] bf16 h (overlays a2)
  int* bsum     = (int*)(ws + o_bsum);
  int* boff     = (int*)(ws + o_boff);

  (void)hipMemsetAsync(ws, 0, zbytes, stream);
  hist_kernel<<<1024, 256, 0, stream>>>(dstE, deg, rank);
  scan1_kernel<<<SCANB, 1024, 0, stream>>>(deg, off, bsum);
  scan2_kernel<<<1, 64, 0, stream>>>(bsum, boff, off + Nn);
  scan3_kernel<<<(Nn + 255) / 256, 256, 0, stream>>>(off, boff);
  scatter_kernel<<<1024, 256, 0, stream>>>(srcE, dstE, off, rank, ssrc);

  convw_kernel<<<1024, 256, 0, stream>>>(wq1, wk1, wv1, ws1, b1, Ff);
  convw_kernel<<<1024, 256, 0, stream>>>(wq2, wk2, wv2, ws2, b2, Dd);
  round_kernel<<<4096, 256, 0, stream>>>(x, a2, Nn, Ff);

  gemm_qs<<<1568, 256, 0, stream>>>(a2, Nn, Ff, b1, bq1, bs1, qb, sb);
  gemm_kv<<<1568, 256, 0, stream>>>(a2, Nn, Ff, b1, bk1, bv1, kvb);
  attn_kernel<<<(Nn + 3) / 4, 256, 0, stream>>>(qb, kvb, sb, off, ssrc, hb);
  gemm_qs<<<1568, 256, 0, stream>>>(hb, Nn, Dd, b2, bq2, bs2, qb, sb);
  gemm_kv<<<1568, 256, 0, stream>>>(hb, Nn, Dd, b2, bk2, bv2, kvb);
  attn_kernel<<<(Nn + 3) / 4, 256, 0, stream>>>(qb, kvb, sb, off, ssrc, hb);

  pool_kernel<<<(Nn + 127) / 128, 256, 0, stream>>>(hb, batch, pooled);
  fc_kernel<<<1, 512, 0, stream>>>(pooled, wf1, bf1, wf2, bf2, outp);
}

// Round 16
// 453.929 us; speedup vs baseline: 1.1256x; 1.1256x over previous
//
#include <hip/hip_runtime.h>
#include <cstdio>

#define Nn 50000
#define Ee 800000
#define Ff 512
#define Dd 256
#define Gg 8
#define SCANB 49   // ceil(Nn/1024)

typedef short short8 __attribute__((ext_vector_type(8)));
typedef __bf16 bf16x8 __attribute__((ext_vector_type(8)));
typedef float f32x4 __attribute__((ext_vector_type(4)));
typedef float f32x2 __attribute__((ext_vector_type(2)));
typedef _Float16 half2v __attribute__((ext_vector_type(2)));

#if defined(__has_builtin)
#if __has_builtin(__builtin_amdgcn_cvt_f32_fp8)
#define HAS_CVTFP8 1
#endif
#if __has_builtin(__builtin_amdgcn_cvt_pk_f32_fp8)
#define HAS_PKFP8 1
#endif
#endif

__device__ inline unsigned short f2bf(float f) {
  unsigned u = __float_as_uint(f);
  u += 0x7FFFu + ((u >> 16) & 1u);
  return (unsigned short)(u >> 16);
}
__device__ inline float bf2f(unsigned short h) {
  return __uint_as_float(((unsigned)h) << 16);
}

// OCP e4m3 encode (RNE, clamp to +-448, denormals handled)
__device__ inline unsigned char f2fp8(float f) {
  const float af = fabsf(f);
  const unsigned s = (f < 0.f) ? 0x80u : 0u;
  if (af >= 448.f) return (unsigned char)(s | 0x7E);
  if (af < 0.015625f) {
    int q = (int)(af * 512.f + 0.5f);
    return (unsigned char)(s | q);
  }
  unsigned u = __float_as_uint(af);
  unsigned m = u & 0x7fffffu;
  unsigned e = u >> 23;
  unsigned r = m + 0x7ffffu + ((m >> 20) & 1u);
  if (r >> 23) { e += 1; r = 0; }
  unsigned em = ((e - 120u) << 3) | ((r >> 20) & 7u);
  if (em > 0x7Eu) em = 0x7Eu;
  return (unsigned char)(s | em);
}

// OCP e4m3 decode, byte SEL of a dword (compile-time constant)
template <int SEL>
__device__ inline float fp8tof(unsigned v) {
#ifdef HAS_CVTFP8
  return __builtin_amdgcn_cvt_f32_fp8(v, SEL);
#else
  unsigned b = (v >> (SEL * 8)) & 0xffu;
  unsigned em = b & 0x7fu;
  float n = __uint_as_float((em << 20) + 0x3C000000u);
  float dn = (float)em * 0.001953125f;
  float r = (em < 8u) ? dn : n;
  return (b & 0x80u) ? -r : r;
#endif
}

// packed fp8 pair decode: bytes [1:0] (hi=false) or [3:2] (hi=true)
template <bool HI>
__device__ inline f32x2 pk8(unsigned w) {
#ifdef HAS_PKFP8
  return __builtin_amdgcn_cvt_pk_f32_fp8((int)w, HI);
#else
  f32x2 r;
  if (HI) { r[0] = fp8tof<2>(w); r[1] = fp8tof<3>(w); }
  else    { r[0] = fp8tof<0>(w); r[1] = fp8tof<1>(w); }
  return r;
#endif
}

__device__ inline void gload16(const void* g, void* l) {
  __builtin_amdgcn_global_load_lds((const __attribute__((address_space(1))) void*)g,
                                   (__attribute__((address_space(3))) void*)l, 16, 0, 0);
}

// ---------------- CSR build (rank-based: one atomic pass) ----------------

__global__ void hist_kernel(const int* __restrict__ dst, int* __restrict__ deg,
                            int* __restrict__ rank) {
  int i = blockIdx.x * blockDim.x + threadIdx.x;
  int stride = gridDim.x * blockDim.x;
  for (; i < Ee; i += stride) rank[i] = atomicAdd(&deg[dst[i]], 1);
}

__global__ __launch_bounds__(1024) void scan1_kernel(const int* __restrict__ deg,
                                                     int* __restrict__ off,
                                                     int* __restrict__ bsum) {
  __shared__ int wsum[16];
  int tid = threadIdx.x, lane = tid & 63, w = tid >> 6;
  int i = blockIdx.x * 1024 + tid;
  int v = (i < Nn) ? deg[i] : 0;
  int x = v;
#pragma unroll
  for (int o = 1; o < 64; o <<= 1) {
    int t = __shfl_up(x, o);
    if (lane >= o) x += t;
  }
  if (lane == 63) wsum[w] = x;
  __syncthreads();
  if (w == 0 && lane < 16) {
    int y = wsum[lane];
#pragma unroll
    for (int o = 1; o < 16; o <<= 1) {
      int t = __shfl_up(y, o);
      if (lane >= o) y += t;
    }
    wsum[lane] = y;
  }
  __syncthreads();
  int incl = x + (w ? wsum[w - 1] : 0);
  if (i < Nn) off[i] = incl - v;
  if (tid == 1023) bsum[blockIdx.x] = incl;
}

__global__ void scan2_kernel(const int* __restrict__ bsum, int* __restrict__ boff,
                             int* __restrict__ offN) {
  int lane = threadIdx.x;
  int v = (lane < SCANB) ? bsum[lane] : 0;
  int x = v;
#pragma unroll
  for (int o = 1; o < 64; o <<= 1) {
    int t = __shfl_up(x, o);
    if (lane >= o) x += t;
  }
  if (lane < SCANB) boff[lane] = x - v;
  if (lane == 63) *offN = x;
}

__global__ void scan3_kernel(int* __restrict__ off, const int* __restrict__ boff) {
  int i = blockIdx.x * 256 + threadIdx.x;
  if (i < Nn) off[i] += boff[i >> 10];
}

__global__ void scatter_kernel(const int* __restrict__ src, const int* __restrict__ dst,
                               const int* __restrict__ off, const int* __restrict__ rank,
                               int* __restrict__ ssrc) {
  int i = blockIdx.x * blockDim.x + threadIdx.x;
  int stride = gridDim.x * blockDim.x;
  for (; i < Ee; i += stride) {
    ssrc[off[dst[i]] + rank[i]] = src[i];
  }
}

// ---------------- conversions ----------------

__global__ void round_kernel(const float* __restrict__ in, unsigned short* __restrict__ out,
                             int M, int K) {
  const int kg4 = K >> 2;
  int i = blockIdx.x * blockDim.x + threadIdx.x;
  const int total = M * kg4;
  const int stride = gridDim.x * blockDim.x;
  for (; i < total; i += stride) {
    const int row = i / kg4, kg = i - row * kg4;
    const float4 v = *(const float4*)(in + (size_t)row * K + kg * 4);
    ushort4 h;
    h.x = f2bf(v.x); h.y = f2bf(v.y); h.z = f2bf(v.z); h.w = f2bf(v.w);
    *(ushort4*)(out + (size_t)row * K + kg * 4) = h;
  }
}

// 4x W [K][256] fp32 -> B [1024][K] bf16 hi-only, transposed; row n = z*256+c
__global__ void convw_kernel(const float* __restrict__ W0, const float* __restrict__ W1,
                             const float* __restrict__ W2, const float* __restrict__ W3,
                             unsigned short* __restrict__ B, int K) {
  int i = blockIdx.x * blockDim.x + threadIdx.x;
  const int total = 1024 * K;
  const int stride = gridDim.x * blockDim.x;
  for (; i < total; i += stride) {
    const int n = i & 1023;
    const int k = i >> 10;
    const int z = n >> 8, c = n & 255;
    const float* W = z == 0 ? W0 : z == 1 ? W1 : z == 2 ? W2 : W3;
    B[(size_t)n * K + k] = f2bf(W[(size_t)k * Dd + c]);
  }
}

// ---------------- 1-term bf16 MFMA GEMM (128x128 tile) with XOR-swizzled LDS epilogue ----
// C = A_bf16 @ B_hi + bias.  A [M][K] bf16, B [1024][K] bf16.
// z=(i2&7)>>1: 0 -> q fp16 [M][256]; 1 -> K fp8 in kv[row*512 + c];
// 2 -> V fp8 in kv[row*512 + 256 + c]; 3 -> s fp16 [M][256].

__global__ __launch_bounds__(256, 6)
void gemm_mfma(const unsigned short* __restrict__ A2, int M, int K,
               const unsigned short* __restrict__ B,
               const float* __restrict__ b0, const float* __restrict__ b1,
               const float* __restrict__ b2, const float* __restrict__ b3,
               _Float16* __restrict__ qout, unsigned char* __restrict__ kvout,
               _Float16* __restrict__ sout) {
  __shared__ __align__(16) char smem[32768];
  unsigned short* As = (unsigned short*)smem;
  unsigned short* Bs = (unsigned short*)(smem + 16384);
  const int tid = threadIdx.x;
  const int lane = tid & 63, w = tid >> 6;
  const int wr = w >> 1, wc = w & 1;
  const int p = blockIdx.x;
  const int xcd = p & 7;
  const int i2 = p >> 3;
  const int bm = (xcd * 49 + (i2 >> 3)) * 128;
  const int zblk = (i2 & 7) >> 1;
  const int colbase = (i2 & 1) * 128;          // block's 128 cols within its z
  const int lda = K, ldb = K;
  const int nsteps = K >> 6;
  const int srow = lane >> 3, sslot = lane & 7;
  const int fr = lane & 15, fq = lane >> 4;

  f32x4 acc[4][4] = {};

  for (int s = 0; s < nsteps; ++s) {
    const int kk = s << 6;
    __syncthreads();
#pragma unroll
    for (int h = 0; h < 4; ++h) {
      const int q = h * 4 + w;
      const int r = q * 8 + srow;
      const int g = sslot ^ (r & 7);
      int ga = bm + r; if (ga > M - 1) ga = M - 1;
      gload16(A2 + (size_t)ga * lda + kk + g * 8, (char*)As + q * 1024);
      const int gb = (zblk * 256 + colbase) + r;   // B row = z*256 + c
      gload16(B + (size_t)gb * ldb + kk + g * 8, (char*)Bs + q * 1024);
    }
    __syncthreads();
    short8 av[2][4], bv[2][4];
#pragma unroll
    for (int kh = 0; kh < 2; ++kh)
#pragma unroll
      for (int i = 0; i < 4; ++i) {
        const int ra = wr * 64 + i * 16 + fr;
        av[kh][i] = *(const short8*)((const char*)As + ra * 128 + (((kh * 4 + fq) ^ (ra & 7)) << 4));
        const int rb = wc * 64 + i * 16 + fr;
        bv[kh][i] = *(const short8*)((const char*)Bs + rb * 128 + (((kh * 4 + fq) ^ (rb & 7)) << 4));
      }
#pragma unroll
    for (int kh = 0; kh < 2; ++kh)
#pragma unroll
      for (int mi = 0; mi < 4; ++mi)
#pragma unroll
        for (int ni = 0; ni < 4; ++ni)
          acc[mi][ni] = __builtin_amdgcn_mfma_f32_16x16x32_bf16(
              __builtin_bit_cast(bf16x8, av[kh][mi]),
              __builtin_bit_cast(bf16x8, bv[kh][ni]), acc[mi][ni], 0, 0, 0);
  }

  // ---- epilogue: fragments -> LDS (row stride 256B, byte XOR ^((row&7)<<4)) ----
  const float* bp = zblk == 0 ? b0 : zblk == 1 ? b1 : zblk == 2 ? b2 : b3;
  __syncthreads();   // K-loop LDS reads done before overwrite
  if (zblk == 1 || zblk == 2) {
    unsigned char* S8 = (unsigned char*)smem;
#pragma unroll
    for (int mi = 0; mi < 4; ++mi)
#pragma unroll
      for (int ni = 0; ni < 4; ++ni) {
        const int col = wc * 64 + ni * 16 + fr;
        const float bias = bp[colbase + col];
#pragma unroll
        for (int j = 0; j < 4; ++j) {
          const int row = wr * 64 + mi * 16 + fq * 4 + j;
          S8[row * 256 + (col ^ ((row & 7) << 4))] = f2fp8(acc[mi][ni][j] + bias);
        }
      }
  } else {
#pragma unroll
    for (int mi = 0; mi < 4; ++mi)
#pragma unroll
      for (int ni = 0; ni < 4; ++ni) {
        const int col = wc * 64 + ni * 16 + fr;
        const float bias = bp[colbase + col];
#pragma unroll
        for (int j = 0; j < 4; ++j) {
          const int row = wr * 64 + mi * 16 + fq * 4 + j;
          *(_Float16*)(smem + row * 256 + ((col * 2) ^ ((row & 7) << 4))) =
              (_Float16)(acc[mi][ni][j] + bias);
        }
      }
  }
  __syncthreads();

  // ---- flush: coalesced 16B stores; fp8 64B/thread-half, fp16 128B/thread-half ----
  const int row = tid >> 1, half = tid & 1;
  const int grow = bm + row;
  if (grow < M) {
    const int sh = (row & 7) << 4;
    if (zblk == 1 || zblk == 2) {
      uint4* dstp = (uint4*)(kvout + (size_t)grow * 512 + (zblk == 2 ? 256 : 0) +
                             colbase + half * 64);
#pragma unroll
      for (int k = 0; k < 4; ++k)
        dstp[k] = *(const uint4*)(smem + row * 256 + ((half * 64 + k * 16) ^ sh));
    } else {
      char* dbase = zblk == 0 ? (char*)qout + (size_t)grow * 512 + colbase * 2
                              : (char*)sout + (size_t)grow * 512 + colbase * 2;
      uint4* dstp = (uint4*)(dbase + half * 128);
#pragma unroll
      for (int k = 0; k < 8; ++k)
        dstp[k] = *(const uint4*)(smem + row * 256 + ((half * 128 + k * 16) ^ sh));
    }
  }
}

// ---------------- per-node attention: half-wave edge pairing ----------------
// One wave per dst node. Lanes 0-31 process even edges, 32-63 odd edges.
// Channel layout: lane hl (=lane&31) owns channels 8hl..8hl+7.
// Heads (H=2, C=128): head0 = lanes 0-15 of each half, head1 = lanes 16-31.
// Score reduce = 4 shfl steps over 16 lanes. Final cross-half softmax merge.
// q fp16 [Nn][256]; kv row 512B: K fp8 [0,256), V fp8 [256,512); s fp16; out bf16.

__global__ __launch_bounds__(256)
void attn_kernel(const _Float16* __restrict__ qbuf, const unsigned char* __restrict__ kvb,
                 const _Float16* __restrict__ sbuf, const int* __restrict__ off,
                 const int* __restrict__ ssrc, unsigned short* __restrict__ hbout) {
  const int gw = (int)((blockIdx.x * 256 + threadIdx.x) >> 6);
  if (gw >= Nn) return;
  const int lane = threadIdx.x & 63;
  const int half = lane >> 5;
  const int hl = lane & 31;
  const float scale = 0.08838834764831845f;

  // q: 8 fp16 channels -> float
  const uint4 qv = *(const uint4*)((const char*)qbuf + (size_t)gw * 512 + hl * 16);
  float qf[8];
  {
    const half2v h0 = __builtin_bit_cast(half2v, qv.x);
    const half2v h1 = __builtin_bit_cast(half2v, qv.y);
    const half2v h2 = __builtin_bit_cast(half2v, qv.z);
    const half2v h3 = __builtin_bit_cast(half2v, qv.w);
    qf[0] = h0[0]; qf[1] = h0[1]; qf[2] = h1[0]; qf[3] = h1[1];
    qf[4] = h2[0]; qf[5] = h2[1]; qf[6] = h3[0]; qf[7] = h3[1];
  }

  const int e0 = off[gw], e1 = off[gw + 1];
  float m = -3.4e38f, d = 0.f;
  float acc[8] = {};

  for (int e = e0; e < e1; e += 8) {
    int sx[4];
    float vald[4];
#pragma unroll
    for (int t = 0; t < 4; ++t) {
      const int ee = e + 2 * t + half;
      vald[t] = (ee < e1) ? 1.f : 0.f;
      sx[t] = ssrc[ee < e1 ? ee : e1 - 1];
    }
    uint2 ku[4], vu[4];
#pragma unroll
    for (int t = 0; t < 4; ++t) {
      const unsigned char* row = kvb + (size_t)sx[t] * 512;
      ku[t] = *(const uint2*)(row + hl * 8);
      vu[t] = *(const uint2*)(row + 256 + hl * 8);
    }
    float p[4];
#pragma unroll
    for (int t = 0; t < 4; ++t) {
      const f32x2 k01 = pk8<false>(ku[t].x), k23 = pk8<true>(ku[t].x);
      const f32x2 k45 = pk8<false>(ku[t].y), k67 = pk8<true>(ku[t].y);
      float pp = qf[0] * k01[0];
      pp = fmaf(qf[1], k01[1], pp);
      pp = fmaf(qf[2], k23[0], pp);
      pp = fmaf(qf[3], k23[1], pp);
      pp = fmaf(qf[4], k45[0], pp);
      pp = fmaf(qf[5], k45[1], pp);
      pp = fmaf(qf[6], k67[0], pp);
      pp = fmaf(qf[7], k67[1], pp);
      p[t] = pp;
    }
#pragma unroll
    for (int o = 8; o >= 1; o >>= 1)
#pragma unroll
      for (int t = 0; t < 4; ++t) p[t] += __shfl_xor(p[t], o);
    float sct[4];
#pragma unroll
    for (int t = 0; t < 4; ++t)
      sct[t] = vald[t] ? p[t] * scale : -3.4e38f;
    float mx = m;
#pragma unroll
    for (int t = 0; t < 4; ++t) mx = fmaxf(mx, sct[t]);
    const float f = __expf(m - mx);
    float wsum = 0.f;
    float vacc[8] = {};
#pragma unroll
    for (int t = 0; t < 4; ++t) {
      const float wt = __expf(sct[t] - mx) * vald[t];
      wsum += wt;
      const f32x2 v01 = pk8<false>(vu[t].x), v23 = pk8<true>(vu[t].x);
      const f32x2 v45 = pk8<false>(vu[t].y), v67 = pk8<true>(vu[t].y);
      vacc[0] = fmaf(wt, v01[0], vacc[0]);
      vacc[1] = fmaf(wt, v01[1], vacc[1]);
      vacc[2] = fmaf(wt, v23[0], vacc[2]);
      vacc[3] = fmaf(wt, v23[1], vacc[3]);
      vacc[4] = fmaf(wt, v45[0], vacc[4]);
      vacc[5] = fmaf(wt, v45[1], vacc[5]);
      vacc[6] = fmaf(wt, v67[0], vacc[6]);
      vacc[7] = fmaf(wt, v67[1], vacc[7]);
    }
    d = d * f + wsum;
#pragma unroll
    for (int j = 0; j < 8; ++j) acc[j] = fmaf(acc[j], f, vacc[j]);
    m = mx;
  }

  // cross-half online-softmax merge (lane l <-> l+32, same channels & head)
  {
    const float m2 = __shfl_xor(m, 32);
    const float d2 = __shfl_xor(d, 32);
    float acc2[8];
#pragma unroll
    for (int j = 0; j < 8; ++j) acc2[j] = __shfl_xor(acc[j], 32);
    const float M = fmaxf(m, m2);
    const float f1 = __expf(m - M);
    const float f2 = __expf(m2 - M);
    d = d * f1 + d2 * f2;
#pragma unroll
    for (int j = 0; j < 8; ++j) acc[j] = acc[j] * f1 + acc2[j] * f2;
  }

  if (half == 0) {
    const float inv = 1.f / (d + 1e-16f);
    const uint4 sv = *(const uint4*)((const char*)sbuf + (size_t)gw * 512 + hl * 16);
    const half2v s0 = __builtin_bit_cast(half2v, sv.x);
    const half2v s1 = __builtin_bit_cast(half2v, sv.y);
    const half2v s2 = __builtin_bit_cast(half2v, sv.z);
    const half2v s3 = __builtin_bit_cast(half2v, sv.w);
    const float sf[8] = {(float)s0[0], (float)s0[1], (float)s1[0], (float)s1[1],
                         (float)s2[0], (float)s2[1], (float)s3[0], (float)s3[1]};
    unsigned short ob[8];
#pragma unroll
    for (int j = 0; j < 8; ++j)
      ob[j] = f2bf(fmaxf(fmaf(acc[j], inv, sf[j]), 0.f));
    *(uint4*)((char*)hbout + (size_t)gw * 512 + hl * 16) = *(const uint4*)ob;
  }
}

// ---------------- pooling (bf16 input) + fc ----------------

__global__ __launch_bounds__(256)
void pool_kernel(const unsigned short* __restrict__ h, const int* __restrict__ batch,
                 float* __restrict__ pooled) {
  int c = threadIdx.x;
  int n0 = blockIdx.x * 128;
  int n1 = min(n0 + 128, Nn);
  int curg = batch[n0];
  float mx = 0.f;
  for (int n = n0; n < n1; ++n) {
    int g = batch[n];
    if (g != curg) {
      atomicMax((int*)(pooled + curg * Dd + c), __float_as_int(mx));
      mx = 0.f;
      curg = g;
    }
    mx = fmaxf(mx, bf2f(h[(size_t)n * Dd + c]));
  }
  atomicMax((int*)(pooled + curg * Dd + c), __float_as_int(mx));
}

__global__ __launch_bounds__(512)
void fc_kernel(const float* __restrict__ pooled,
               const float* __restrict__ wf1, const float* __restrict__ bf1,
               const float* __restrict__ wf2, const float* __restrict__ bf2,
               float* __restrict__ outp) {
  __shared__ float t[Gg][64];
  int tid = threadIdx.x;
  int g = tid >> 6, j = tid & 63;
  float acc = bf1[j];
  for (int c = 0; c < Dd; ++c) acc = fmaf(pooled[g * Dd + c], wf1[c * 64 + j], acc);
  t[g][j] = acc;
  __syncthreads();
  if (tid < Gg * 4) {
    int gg = tid >> 2, cc = tid & 3;
    float a2 = bf2[cc];
    for (int j2 = 0; j2 < 64; ++j2) a2 = fmaf(t[gg][j2], wf2[j2 * 4 + cc], a2);
    outp[gg * 4 + cc] = a2;
  }
}

// ---------------- host ----------------

extern "C" void kernel_launch(void* const* d_in, const int* in_sizes, int n_in,
                              void* d_out, int out_size, void* d_ws, size_t ws_size,
                              hipStream_t stream) {
  const float* x   = (const float*)d_in[0];
  const int* ei    = (const int*)d_in[1];
  const int* srcE  = ei;
  const int* dstE  = ei + Ee;
  const int* batch = (const int*)d_in[2];
  const float* wq1 = (const float*)d_in[3];  const float* bq1 = (const float*)d_in[4];
  const float* wk1 = (const float*)d_in[5];  const float* bk1 = (const float*)d_in[6];
  const float* wv1 = (const float*)d_in[7];  const float* bv1 = (const float*)d_in[8];
  const float* ws1 = (const float*)d_in[9];  const float* bs1 = (const float*)d_in[10];
  const float* wq2 = (const float*)d_in[11]; const float* bq2 = (const float*)d_in[12];
  const float* wk2 = (const float*)d_in[13]; const float* bk2 = (const float*)d_in[14];
  const float* wv2 = (const float*)d_in[15]; const float* bv2 = (const float*)d_in[16];
  const float* ws2 = (const float*)d_in[17]; const float* bs2 = (const float*)d_in[18];
  const float* wf1 = (const float*)d_in[19]; const float* bf1 = (const float*)d_in[20];
  const float* wf2 = (const float*)d_in[21]; const float* bf2 = (const float*)d_in[22];
  float* outp = (float*)d_out;
  char* ws = (char*)d_ws;

  auto al256 = [](size_t v) { return (v + 255) & ~(size_t)255; };
  size_t o_deg  = 0;
  size_t o_pool = o_deg + (size_t)Nn * 4;
  size_t zbytes = o_pool + (size_t)Gg * Dd * 4;
  size_t o_off  = al256(zbytes);
  size_t o_ssrc = al256(o_off + (size_t)(Nn + 1) * 4);
  size_t o_rank = al256(o_ssrc + (size_t)Ee * 4);
  size_t o_q    = al256(o_rank + (size_t)Ee * 4);                 // fp16 [Nn][256]
  size_t o_kv   = al256(o_q + (size_t)Nn * Dd * 2);               // 512B rows [Nn]
  size_t o_s    = al256(o_kv + (size_t)Nn * 512);                 // fp16 [Nn][256]
  size_t o_b1   = al256(o_s + (size_t)Nn * Dd * 2);               // bf16 [1024][512]
  size_t o_b2   = al256(o_b1 + (size_t)1024 * Ff * 2);            // bf16 [1024][256]
  size_t o_a    = al256(o_b2 + (size_t)1024 * Dd * 2);            // bf16 [Nn][512] x / h overlay
  size_t o_bsum = al256(o_a + (size_t)Nn * Ff * 2);
  size_t o_boff = al256(o_bsum + (size_t)SCANB * 4);
  size_t total  = o_boff + (size_t)SCANB * 4;
  if (ws_size < total) {
    fprintf(stderr, "kernel_launch: ws too small: %zu < %zu\n", ws_size, total);
    return;
  }

  int*   deg    = (int*)(ws + o_deg);
  float* pooled = (float*)(ws + o_pool);
  int*   off    = (int*)(ws + o_off);
  int*   ssrc   = (int*)(ws + o_ssrc);
  int*   rank   = (int*)(ws + o_rank);
  _Float16* qb  = (_Float16*)(ws + o_q);
  unsigned char* kvb = (unsigned char*)(ws + o_kv);
  _Float16* sb  = (_Float16*)(ws + o_s);
  unsigned short* b1 = (unsigned short*)(ws + o_b1);
  unsigned short* b2 = (unsigned short*)(ws + o_b2);
  unsigned short* a2  = (unsigned short*)(ws + o_a);    // [Nn][512] bf16 (x)
  unsigned short* hb  = (unsigned short*)(ws + o_a);    // [Nn][256] bf16 h (overlays a2)
  int* bsum     = (int*)(ws + o_bsum);
  int* boff     = (int*)(ws + o_boff);

  (void)hipMemsetAsync(ws, 0, zbytes, stream);
  hist_kernel<<<1024, 256, 0, stream>>>(dstE, deg, rank);
  scan1_kernel<<<SCANB, 1024, 0, stream>>>(deg, off, bsum);
  scan2_kernel<<<1, 64, 0, stream>>>(bsum, boff, off + Nn);
  scan3_kernel<<<(Nn + 255) / 256, 256, 0, stream>>>(off, boff);
  scatter_kernel<<<1024, 256, 0, stream>>>(srcE, dstE, off, rank, ssrc);

  convw_kernel<<<1024, 256, 0, stream>>>(wq1, wk1, wv1, ws1, b1, Ff);
  convw_kernel<<<1024, 256, 0, stream>>>(wq2, wk2, wv2, ws2, b2, Dd);
  round_kernel<<<4096, 256, 0, stream>>>(x, a2, Nn, Ff);

  gemm_mfma<<<3136, 256, 0, stream>>>(a2, Nn, Ff, b1, bq1, bk1, bv1, bs1, qb, kvb, sb);
  attn_kernel<<<(Nn + 3) / 4, 256, 0, stream>>>(qb, kvb, sb, off, ssrc, hb);
  gemm_mfma<<<3136, 256, 0, stream>>>(hb, Nn, Dd, b2, bq2, bk2, bv2, bs2, qb, kvb, sb);
  attn_kernel<<<(Nn + 3) / 4, 256, 0, stream>>>(qb, kvb, sb, off, ssrc, hb);

  pool_kernel<<<(Nn + 127) / 128, 256, 0, stream>>>(hb, batch, pooled);
  fc_kernel<<<1, 512, 0, stream>>>(pooled, wf1, bf1, wf2, bf2, outp);
}

// Round 17
// 416.044 us; speedup vs baseline: 1.2281x; 1.0911x over previous
//
#include <hip/hip_runtime.h>
#include <cstdio>

#define Nn 50000
#define Ee 800000
#define Ff 512
#define Dd 256
#define Gg 8
#define SCANB 49   // ceil(Nn/1024)

typedef short short8 __attribute__((ext_vector_type(8)));
typedef __bf16 bf16x8 __attribute__((ext_vector_type(8)));
typedef float f32x4 __attribute__((ext_vector_type(4)));
typedef float f32x2 __attribute__((ext_vector_type(2)));
typedef _Float16 half2v __attribute__((ext_vector_type(2)));

#if defined(__has_builtin)
#if __has_builtin(__builtin_amdgcn_cvt_f32_fp8)
#define HAS_CVTFP8 1
#endif
#if __has_builtin(__builtin_amdgcn_cvt_pk_f32_fp8)
#define HAS_PKFP8 1
#endif
#if __has_builtin(__builtin_amdgcn_cvt_pk_fp8_f32)
#define HAS_PKFP8E 1
#endif
#endif

__device__ inline unsigned short f2bf(float f) {
  unsigned u = __float_as_uint(f);
  u += 0x7FFFu + ((u >> 16) & 1u);
  return (unsigned short)(u >> 16);
}
__device__ inline float bf2f(unsigned short h) {
  return __uint_as_float(((unsigned)h) << 16);
}

// OCP e4m3 encode (RNE, clamp to +-448, denormals handled) — software fallback
__device__ inline unsigned char f2fp8(float f) {
  const float af = fabsf(f);
  const unsigned s = (f < 0.f) ? 0x80u : 0u;
  if (af >= 448.f) return (unsigned char)(s | 0x7E);
  if (af < 0.015625f) {
    int q = (int)(af * 512.f + 0.5f);
    return (unsigned char)(s | q);
  }
  unsigned u = __float_as_uint(af);
  unsigned m = u & 0x7fffffu;
  unsigned e = u >> 23;
  unsigned r = m + 0x7ffffu + ((m >> 20) & 1u);
  if (r >> 23) { e += 1; r = 0; }
  unsigned em = ((e - 120u) << 3) | ((r >> 20) & 7u);
  if (em > 0x7Eu) em = 0x7Eu;
  return (unsigned char)(s | em);
}

// packed fp8 encode: 2 f32 -> u32 with bytes[0]=fp8(a), bytes[1]=fp8(b)
__device__ inline unsigned pk8e(float a, float b) {
#ifdef HAS_PKFP8E
  return (unsigned)__builtin_amdgcn_cvt_pk_fp8_f32(a, b, 0, false);
#else
  return (unsigned)f2fp8(a) | ((unsigned)f2fp8(b) << 8);
#endif
}

// OCP e4m3 decode, byte SEL of a dword (compile-time constant)
template <int SEL>
__device__ inline float fp8tof(unsigned v) {
#ifdef HAS_CVTFP8
  return __builtin_amdgcn_cvt_f32_fp8(v, SEL);
#else
  unsigned b = (v >> (SEL * 8)) & 0xffu;
  unsigned em = b & 0x7fu;
  float n = __uint_as_float((em << 20) + 0x3C000000u);
  float dn = (float)em * 0.001953125f;
  float r = (em < 8u) ? dn : n;
  return (b & 0x80u) ? -r : r;
#endif
}

// packed fp8 pair decode: bytes [1:0] (hi=false) or [3:2] (hi=true)
template <bool HI>
__device__ inline f32x2 pk8(unsigned w) {
#ifdef HAS_PKFP8
  return __builtin_amdgcn_cvt_pk_f32_fp8((int)w, HI);
#else
  f32x2 r;
  if (HI) { r[0] = fp8tof<2>(w); r[1] = fp8tof<3>(w); }
  else    { r[0] = fp8tof<0>(w); r[1] = fp8tof<1>(w); }
  return r;
#endif
}

__device__ inline void gload16(const void* g, void* l) {
  __builtin_amdgcn_global_load_lds((const __attribute__((address_space(1))) void*)g,
                                   (__attribute__((address_space(3))) void*)l, 16, 0, 0);
}

// ---------------- CSR build (rank-based: one atomic pass) ----------------

__global__ void hist_kernel(const int* __restrict__ dst, int* __restrict__ deg,
                            int* __restrict__ rank) {
  int i = blockIdx.x * blockDim.x + threadIdx.x;
  int stride = gridDim.x * blockDim.x;
  for (; i < Ee; i += stride) rank[i] = atomicAdd(&deg[dst[i]], 1);
}

__global__ __launch_bounds__(1024) void scan1_kernel(const int* __restrict__ deg,
                                                     int* __restrict__ off,
                                                     int* __restrict__ bsum) {
  __shared__ int wsum[16];
  int tid = threadIdx.x, lane = tid & 63, w = tid >> 6;
  int i = blockIdx.x * 1024 + tid;
  int v = (i < Nn) ? deg[i] : 0;
  int x = v;
#pragma unroll
  for (int o = 1; o < 64; o <<= 1) {
    int t = __shfl_up(x, o);
    if (lane >= o) x += t;
  }
  if (lane == 63) wsum[w] = x;
  __syncthreads();
  if (w == 0 && lane < 16) {
    int y = wsum[lane];
#pragma unroll
    for (int o = 1; o < 16; o <<= 1) {
      int t = __shfl_up(y, o);
      if (lane >= o) y += t;
    }
    wsum[lane] = y;
  }
  __syncthreads();
  int incl = x + (w ? wsum[w - 1] : 0);
  if (i < Nn) off[i] = incl - v;
  if (tid == 1023) bsum[blockIdx.x] = incl;
}

__global__ void scan2_kernel(const int* __restrict__ bsum, int* __restrict__ boff,
                             int* __restrict__ offN) {
  int lane = threadIdx.x;
  int v = (lane < SCANB) ? bsum[lane] : 0;
  int x = v;
#pragma unroll
  for (int o = 1; o < 64; o <<= 1) {
    int t = __shfl_up(x, o);
    if (lane >= o) x += t;
  }
  if (lane < SCANB) boff[lane] = x - v;
  if (lane == 63) *offN = x;
}

__global__ void scan3_kernel(int* __restrict__ off, const int* __restrict__ boff) {
  int i = blockIdx.x * 256 + threadIdx.x;
  if (i < Nn) off[i] += boff[i >> 10];
}

__global__ void scatter_kernel(const int* __restrict__ src, const int* __restrict__ dst,
                               const int* __restrict__ off, const int* __restrict__ rank,
                               int* __restrict__ ssrc) {
  int i = blockIdx.x * blockDim.x + threadIdx.x;
  int stride = gridDim.x * blockDim.x;
  for (; i < Ee; i += stride) {
    ssrc[off[dst[i]] + rank[i]] = src[i];
  }
}

// ---------------- conversions ----------------

__global__ void round_kernel(const float* __restrict__ in, unsigned short* __restrict__ out,
                             int M, int K) {
  const int kg4 = K >> 2;
  int i = blockIdx.x * blockDim.x + threadIdx.x;
  const int total = M * kg4;
  const int stride = gridDim.x * blockDim.x;
  for (; i < total; i += stride) {
    const int row = i / kg4, kg = i - row * kg4;
    const float4 v = *(const float4*)(in + (size_t)row * K + kg * 4);
    ushort4 h;
    h.x = f2bf(v.x); h.y = f2bf(v.y); h.z = f2bf(v.z); h.w = f2bf(v.w);
    *(ushort4*)(out + (size_t)row * K + kg * 4) = h;
  }
}

// 4x W [K][256] fp32 -> B [1024][K] bf16 hi-only, transposed; row n = z*256+c
__global__ void convw_kernel(const float* __restrict__ W0, const float* __restrict__ W1,
                             const float* __restrict__ W2, const float* __restrict__ W3,
                             unsigned short* __restrict__ B, int K) {
  int i = blockIdx.x * blockDim.x + threadIdx.x;
  const int total = 1024 * K;
  const int stride = gridDim.x * blockDim.x;
  for (; i < total; i += stride) {
    const int n = i & 1023;
    const int k = i >> 10;
    const int z = n >> 8, c = n & 255;
    const float* W = z == 0 ? W0 : z == 1 ? W1 : z == 2 ? W2 : W3;
    B[(size_t)n * K + k] = f2bf(W[(size_t)k * Dd + c]);
  }
}

// ---------------- 1-term bf16 MFMA GEMM (128x128 tile) with XOR-swizzled LDS epilogue ----
// C = A_bf16 @ B_hi + bias.  A [M][K] bf16, B [1024][K] bf16.
// z=(i2&7)>>1: 0 -> q fp16 [M][256]; 1 -> K fp8 in kv[row*512 + c];
// 2 -> V fp8 in kv[row*512 + 256 + c]; 3 -> s fp16 [M][256].

__global__ __launch_bounds__(256)
void gemm_mfma(const unsigned short* __restrict__ A2, int M, int K,
               const unsigned short* __restrict__ B,
               const float* __restrict__ b0, const float* __restrict__ b1,
               const float* __restrict__ b2, const float* __restrict__ b3,
               _Float16* __restrict__ qout, unsigned char* __restrict__ kvout,
               _Float16* __restrict__ sout) {
  __shared__ __align__(16) char smem[32768];
  unsigned short* As = (unsigned short*)smem;
  unsigned short* Bs = (unsigned short*)(smem + 16384);
  const int tid = threadIdx.x;
  const int lane = tid & 63, w = tid >> 6;
  const int wr = w >> 1, wc = w & 1;
  const int p = blockIdx.x;
  const int xcd = p & 7;
  const int i2 = p >> 3;
  const int bm = (xcd * 49 + (i2 >> 3)) * 128;
  const int zblk = (i2 & 7) >> 1;
  const int colbase = (i2 & 1) * 128;          // block's 128 cols within its z
  const int lda = K, ldb = K;
  const int nsteps = K >> 6;
  const int srow = lane >> 3, sslot = lane & 7;
  const int fr = lane & 15, fq = lane >> 4;

  f32x4 acc[4][4] = {};

  for (int s = 0; s < nsteps; ++s) {
    const int kk = s << 6;
    __syncthreads();
#pragma unroll
    for (int h = 0; h < 4; ++h) {
      const int q = h * 4 + w;
      const int r = q * 8 + srow;
      const int g = sslot ^ (r & 7);
      int ga = bm + r; if (ga > M - 1) ga = M - 1;
      gload16(A2 + (size_t)ga * lda + kk + g * 8, (char*)As + q * 1024);
      const int gb = (zblk * 256 + colbase) + r;   // B row = z*256 + c
      gload16(B + (size_t)gb * ldb + kk + g * 8, (char*)Bs + q * 1024);
    }
    __syncthreads();
    short8 av[2][4], bv[2][4];
#pragma unroll
    for (int kh = 0; kh < 2; ++kh)
#pragma unroll
      for (int i = 0; i < 4; ++i) {
        const int ra = wr * 64 + i * 16 + fr;
        av[kh][i] = *(const short8*)((const char*)As + ra * 128 + (((kh * 4 + fq) ^ (ra & 7)) << 4));
        const int rb = wc * 64 + i * 16 + fr;
        bv[kh][i] = *(const short8*)((const char*)Bs + rb * 128 + (((kh * 4 + fq) ^ (rb & 7)) << 4));
      }
#pragma unroll
    for (int kh = 0; kh < 2; ++kh)
#pragma unroll
      for (int mi = 0; mi < 4; ++mi)
#pragma unroll
        for (int ni = 0; ni < 4; ++ni)
          acc[mi][ni] = __builtin_amdgcn_mfma_f32_16x16x32_bf16(
              __builtin_bit_cast(bf16x8, av[kh][mi]),
              __builtin_bit_cast(bf16x8, bv[kh][ni]), acc[mi][ni], 0, 0, 0);
  }

  // ---- epilogue: fragments -> LDS (row stride 256B, byte XOR ^((row&7)<<4)) ----
  const float* bp = zblk == 0 ? b0 : zblk == 1 ? b1 : zblk == 2 ? b2 : b3;
  __syncthreads();   // K-loop LDS reads done before overwrite
  if (zblk == 1 || zblk == 2) {
    unsigned char* S8 = (unsigned char*)smem;
#pragma unroll
    for (int mi = 0; mi < 4; ++mi)
#pragma unroll
      for (int ni = 0; ni < 4; ++ni) {
        const int col = wc * 64 + ni * 16 + fr;
        const float bias = bp[colbase + col];
        const int row0 = wr * 64 + mi * 16 + fq * 4;
        const unsigned pk01 = pk8e(acc[mi][ni][0] + bias, acc[mi][ni][1] + bias);
        const unsigned pk23 = pk8e(acc[mi][ni][2] + bias, acc[mi][ni][3] + bias);
        S8[(row0 + 0) * 256 + (col ^ (((row0 + 0) & 7) << 4))] = (unsigned char)pk01;
        S8[(row0 + 1) * 256 + (col ^ (((row0 + 1) & 7) << 4))] = (unsigned char)(pk01 >> 8);
        S8[(row0 + 2) * 256 + (col ^ (((row0 + 2) & 7) << 4))] = (unsigned char)pk23;
        S8[(row0 + 3) * 256 + (col ^ (((row0 + 3) & 7) << 4))] = (unsigned char)(pk23 >> 8);
      }
  } else {
#pragma unroll
    for (int mi = 0; mi < 4; ++mi)
#pragma unroll
      for (int ni = 0; ni < 4; ++ni) {
        const int col = wc * 64 + ni * 16 + fr;
        const float bias = bp[colbase + col];
#pragma unroll
        for (int j = 0; j < 4; ++j) {
          const int row = wr * 64 + mi * 16 + fq * 4 + j;
          *(_Float16*)(smem + row * 256 + ((col * 2) ^ ((row & 7) << 4))) =
              (_Float16)(acc[mi][ni][j] + bias);
        }
      }
  }
  __syncthreads();

  // ---- flush: coalesced 16B stores; fp8 64B/thread-half, fp16 128B/thread-half ----
  const int row = tid >> 1, half = tid & 1;
  const int grow = bm + row;
  if (grow < M) {
    const int sh = (row & 7) << 4;
    if (zblk == 1 || zblk == 2) {
      uint4* dstp = (uint4*)(kvout + (size_t)grow * 512 + (zblk == 2 ? 256 : 0) +
                             colbase + half * 64);
#pragma unroll
      for (int k = 0; k < 4; ++k)
        dstp[k] = *(const uint4*)(smem + row * 256 + ((half * 64 + k * 16) ^ sh));
    } else {
      char* dbase = zblk == 0 ? (char*)qout + (size_t)grow * 512 + colbase * 2
                              : (char*)sout + (size_t)grow * 512 + colbase * 2;
      uint4* dstp = (uint4*)(dbase + half * 128);
#pragma unroll
      for (int k = 0; k < 8; ++k)
        dstp[k] = *(const uint4*)(smem + row * 256 + ((half * 128 + k * 16) ^ sh));
    }
  }
}

// ---------------- per-node attention: half-wave edge pairing ----------------
// One wave per dst node. Lanes 0-31 process even edges, 32-63 odd edges.
// Channel layout: lane hl (=lane&31) owns channels 8hl..8hl+7.
// Heads (H=2, C=128): head0 = lanes 0-15 of each half, head1 = lanes 16-31.
// Score reduce = 4 shfl steps over 16 lanes. Final cross-half softmax merge.
// q fp16 [Nn][256]; kv row 512B: K fp8 [0,256), V fp8 [256,512); s fp16; out bf16.

__global__ __launch_bounds__(256)
void attn_kernel(const _Float16* __restrict__ qbuf, const unsigned char* __restrict__ kvb,
                 const _Float16* __restrict__ sbuf, const int* __restrict__ off,
                 const int* __restrict__ ssrc, unsigned short* __restrict__ hbout) {
  const int gw = (int)((blockIdx.x * 256 + threadIdx.x) >> 6);
  if (gw >= Nn) return;
  const int lane = threadIdx.x & 63;
  const int half = lane >> 5;
  const int hl = lane & 31;
  const float scale = 0.08838834764831845f;

  // q: 8 fp16 channels -> float
  const uint4 qv = *(const uint4*)((const char*)qbuf + (size_t)gw * 512 + hl * 16);
  float qf[8];
  {
    const half2v h0 = __builtin_bit_cast(half2v, qv.x);
    const half2v h1 = __builtin_bit_cast(half2v, qv.y);
    const half2v h2 = __builtin_bit_cast(half2v, qv.z);
    const half2v h3 = __builtin_bit_cast(half2v, qv.w);
    qf[0] = h0[0]; qf[1] = h0[1]; qf[2] = h1[0]; qf[3] = h1[1];
    qf[4] = h2[0]; qf[5] = h2[1]; qf[6] = h3[0]; qf[7] = h3[1];
  }

  const int e0 = off[gw], e1 = off[gw + 1];
  float m = -3.4e38f, d = 0.f;
  float acc[8] = {};

  for (int e = e0; e < e1; e += 8) {
    int sx[4];
    float vald[4];
#pragma unroll
    for (int t = 0; t < 4; ++t) {
      const int ee = e + 2 * t + half;
      vald[t] = (ee < e1) ? 1.f : 0.f;
      sx[t] = ssrc[ee < e1 ? ee : e1 - 1];
    }
    uint2 ku[4], vu[4];
#pragma unroll
    for (int t = 0; t < 4; ++t) {
      const unsigned char* row = kvb + (size_t)sx[t] * 512;
      ku[t] = *(const uint2*)(row + hl * 8);
      vu[t] = *(const uint2*)(row + 256 + hl * 8);
    }
    float p[4];
#pragma unroll
    for (int t = 0; t < 4; ++t) {
      const f32x2 k01 = pk8<false>(ku[t].x), k23 = pk8<true>(ku[t].x);
      const f32x2 k45 = pk8<false>(ku[t].y), k67 = pk8<true>(ku[t].y);
      float pp = qf[0] * k01[0];
      pp = fmaf(qf[1], k01[1], pp);
      pp = fmaf(qf[2], k23[0], pp);
      pp = fmaf(qf[3], k23[1], pp);
      pp = fmaf(qf[4], k45[0], pp);
      pp = fmaf(qf[5], k45[1], pp);
      pp = fmaf(qf[6], k67[0], pp);
      pp = fmaf(qf[7], k67[1], pp);
      p[t] = pp;
    }
#pragma unroll
    for (int o = 8; o >= 1; o >>= 1)
#pragma unroll
      for (int t = 0; t < 4; ++t) p[t] += __shfl_xor(p[t], o);
    float sct[4];
#pragma unroll
    for (int t = 0; t < 4; ++t)
      sct[t] = vald[t] ? p[t] * scale : -3.4e38f;
    float mx = m;
#pragma unroll
    for (int t = 0; t < 4; ++t) mx = fmaxf(mx, sct[t]);
    const float f = __expf(m - mx);
    float wsum = 0.f;
    float vacc[8] = {};
#pragma unroll
    for (int t = 0; t < 4; ++t) {
      const float wt = __expf(sct[t] - mx) * vald[t];
      wsum += wt;
      const f32x2 v01 = pk8<false>(vu[t].x), v23 = pk8<true>(vu[t].x);
      const f32x2 v45 = pk8<false>(vu[t].y), v67 = pk8<true>(vu[t].y);
      vacc[0] = fmaf(wt, v01[0], vacc[0]);
      vacc[1] = fmaf(wt, v01[1], vacc[1]);
      vacc[2] = fmaf(wt, v23[0], vacc[2]);
      vacc[3] = fmaf(wt, v23[1], vacc[3]);
      vacc[4] = fmaf(wt, v45[0], vacc[4]);
      vacc[5] = fmaf(wt, v45[1], vacc[5]);
      vacc[6] = fmaf(wt, v67[0], vacc[6]);
      vacc[7] = fmaf(wt, v67[1], vacc[7]);
    }
    d = d * f + wsum;
#pragma unroll
    for (int j = 0; j < 8; ++j) acc[j] = fmaf(acc[j], f, vacc[j]);
    m = mx;
  }

  // cross-half online-softmax merge (lane l <-> l+32, same channels & head)
  {
    const float m2 = __shfl_xor(m, 32);
    const float d2 = __shfl_xor(d, 32);
    float acc2[8];
#pragma unroll
    for (int j = 0; j < 8; ++j) acc2[j] = __shfl_xor(acc[j], 32);
    const float M = fmaxf(m, m2);
    const float f1 = __expf(m - M);
    const float f2 = __expf(m2 - M);
    d = d * f1 + d2 * f2;
#pragma unroll
    for (int j = 0; j < 8; ++j) acc[j] = acc[j] * f1 + acc2[j] * f2;
  }

  if (half == 0) {
    const float inv = 1.f / (d + 1e-16f);
    const uint4 sv = *(const uint4*)((const char*)sbuf + (size_t)gw * 512 + hl * 16);
    const half2v s0 = __builtin_bit_cast(half2v, sv.x);
    const half2v s1 = __builtin_bit_cast(half2v, sv.y);
    const half2v s2 = __builtin_bit_cast(half2v, sv.z);
    const half2v s3 = __builtin_bit_cast(half2v, sv.w);
    const float sf[8] = {(float)s0[0], (float)s0[1], (float)s1[0], (float)s1[1],
                         (float)s2[0], (float)s2[1], (float)s3[0], (float)s3[1]};
    unsigned short ob[8];
#pragma unroll
    for (int j = 0; j < 8; ++j)
      ob[j] = f2bf(fmaxf(fmaf(acc[j], inv, sf[j]), 0.f));
    *(uint4*)((char*)hbout + (size_t)gw * 512 + hl * 16) = *(const uint4*)ob;
  }
}

// ---------------- pooling (bf16 input) + fc ----------------

__global__ __launch_bounds__(256)
void pool_kernel(const unsigned short* __restrict__ h, const int* __restrict__ batch,
                 float* __restrict__ pooled) {
  int c = threadIdx.x;
  int n0 = blockIdx.x * 128;
  int n1 = min(n0 + 128, Nn);
  int curg = batch[n0];
  float mx = 0.f;
  for (int n = n0; n < n1; ++n) {
    int g = batch[n];
    if (g != curg) {
      atomicMax((int*)(pooled + curg * Dd + c), __float_as_int(mx));
      mx = 0.f;
      curg = g;
    }
    mx = fmaxf(mx, bf2f(h[(size_t)n * Dd + c]));
  }
  atomicMax((int*)(pooled + curg * Dd + c), __float_as_int(mx));
}

__global__ __launch_bounds__(512)
void fc_kernel(const float* __restrict__ pooled,
               const float* __restrict__ wf1, const float* __restrict__ bf1,
               const float* __restrict__ wf2, const float* __restrict__ bf2,
               float* __restrict__ outp) {
  __shared__ float t[Gg][64];
  int tid = threadIdx.x;
  int g = tid >> 6, j = tid & 63;
  float acc = bf1[j];
  for (int c = 0; c < Dd; ++c) acc = fmaf(pooled[g * Dd + c], wf1[c * 64 + j], acc);
  t[g][j] = acc;
  __syncthreads();
  if (tid < Gg * 4) {
    int gg = tid >> 2, cc = tid & 3;
    float a2 = bf2[cc];
    for (int j2 = 0; j2 < 64; ++j2) a2 = fmaf(t[gg][j2], wf2[j2 * 4 + cc], a2);
    outp[gg * 4 + cc] = a2;
  }
}

// ---------------- host ----------------

extern "C" void kernel_launch(void* const* d_in, const int* in_sizes, int n_in,
                              void* d_out, int out_size, void* d_ws, size_t ws_size,
                              hipStream_t stream) {
  const float* x   = (const float*)d_in[0];
  const int* ei    = (const int*)d_in[1];
  const int* srcE  = ei;
  const int* dstE  = ei + Ee;
  const int* batch = (const int*)d_in[2];
  const float* wq1 = (const float*)d_in[3];  const float* bq1 = (const float*)d_in[4];
  const float* wk1 = (const float*)d_in[5];  const float* bk1 = (const float*)d_in[6];
  const float* wv1 = (const float*)d_in[7];  const float* bv1 = (const float*)d_in[8];
  const float* ws1 = (const float*)d_in[9];  const float* bs1 = (const float*)d_in[10];
  const float* wq2 = (const float*)d_in[11]; const float* bq2 = (const float*)d_in[12];
  const float* wk2 = (const float*)d_in[13]; const float* bk2 = (const float*)d_in[14];
  const float* wv2 = (const float*)d_in[15]; const float* bv2 = (const float*)d_in[16];
  const float* ws2 = (const float*)d_in[17]; const float* bs2 = (const float*)d_in[18];
  const float* wf1 = (const float*)d_in[19]; const float* bf1 = (const float*)d_in[20];
  const float* wf2 = (const float*)d_in[21]; const float* bf2 = (const float*)d_in[22];
  float* outp = (float*)d_out;
  char* ws = (char*)d_ws;

  auto al256 = [](size_t v) { return (v + 255) & ~(size_t)255; };
  size_t o_deg  = 0;
  size_t o_pool = o_deg + (size_t)Nn * 4;
  size_t zbytes = o_pool + (size_t)Gg * Dd * 4;
  size_t o_off  = al256(zbytes);
  size_t o_ssrc = al256(o_off + (size_t)(Nn + 1) * 4);
  size_t o_rank = al256(o_ssrc + (size_t)Ee * 4);
  size_t o_q    = al256(o_rank + (size_t)Ee * 4);                 // fp16 [Nn][256]
  size_t o_kv   = al256(o_q + (size_t)Nn * Dd * 2);               // 512B rows [Nn]
  size_t o_s    = al256(o_kv + (size_t)Nn * 512);                 // fp16 [Nn][256]
  size_t o_b1   = al256(o_s + (size_t)Nn * Dd * 2);               // bf16 [1024][512]
  size_t o_b2   = al256(o_b1 + (size_t)1024 * Ff * 2);            // bf16 [1024][256]
  size_t o_a    = al256(o_b2 + (size_t)1024 * Dd * 2);            // bf16 [Nn][512] x / h overlay
  size_t o_bsum = al256(o_a + (size_t)Nn * Ff * 2);
  size_t o_boff = al256(o_bsum + (size_t)SCANB * 4);
  size_t total  = o_boff + (size_t)SCANB * 4;
  if (ws_size < total) {
    fprintf(stderr, "kernel_launch: ws too small: %zu < %zu\n", ws_size, total);
    return;
  }

  int*   deg    = (int*)(ws + o_deg);
  float* pooled = (float*)(ws + o_pool);
  int*   off    = (int*)(ws + o_off);
  int*   ssrc   = (int*)(ws + o_ssrc);
  int*   rank   = (int*)(ws + o_rank);
  _Float16* qb  = (_Float16*)(ws + o_q);
  unsigned char* kvb = (unsigned char*)(ws + o_kv);
  _Float16* sb  = (_Float16*)(ws + o_s);
  unsigned short* b1 = (unsigned short*)(ws + o_b1);
  unsigned short* b2 = (unsigned short*)(ws + o_b2);
  unsigned short* a2  = (unsigned short*)(ws + o_a);    // [Nn][512] bf16 (x)
  unsigned short* hb  = (unsigned short*)(ws + o_a);    // [Nn][256] bf16 h (overlays a2)
  int* bsum     = (int*)(ws + o_bsum);
  int* boff     = (int*)(ws + o_boff);

  (void)hipMemsetAsync(ws, 0, zbytes, stream);
  hist_kernel<<<1024, 256, 0, stream>>>(dstE, deg, rank);
  scan1_kernel<<<SCANB, 1024, 0, stream>>>(deg, off, bsum);
  scan2_kernel<<<1, 64, 0, stream>>>(bsum, boff, off + Nn);
  scan3_kernel<<<(Nn + 255) / 256, 256, 0, stream>>>(off, boff);
  scatter_kernel<<<1024, 256, 0, stream>>>(srcE, dstE, off, rank, ssrc);

  convw_kernel<<<1024, 256, 0, stream>>>(wq1, wk1, wv1, ws1, b1, Ff);
  convw_kernel<<<1024, 256, 0, stream>>>(wq2, wk2, wv2, ws2, b2, Dd);
  round_kernel<<<4096, 256, 0, stream>>>(x, a2, Nn, Ff);

  gemm_mfma<<<3136, 256, 0, stream>>>(a2, Nn, Ff, b1, bq1, bk1, bv1, bs1, qb, kvb, sb);
  attn_kernel<<<(Nn + 3) / 4, 256, 0, stream>>>(qb, kvb, sb, off, ssrc, hb);
  gemm_mfma<<<3136, 256, 0, stream>>>(hb, Nn, Dd, b2, bq2, bk2, bv2, bs2, qb, kvb, sb);
  attn_kernel<<<(Nn + 3) / 4, 256, 0, stream>>>(qb, kvb, sb, off, ssrc, hb);

  pool_kernel<<<(Nn + 127) / 128, 256, 0, stream>>>(hb, batch, pooled);
  fc_kernel<<<1, 512, 0, stream>>>(pooled, wf1, bf1, wf2, bf2, outp);
}

// Round 18
// 388.607 us; speedup vs baseline: 1.3148x; 1.0706x over previous
//
#include <hip/hip_runtime.h>
#include <cstdio>

#define Nn 50000
#define Ee 800000
#define Ff 512
#define Dd 256
#define Gg 8
#define SCANB 49   // ceil(Nn/1024)

typedef short short8 __attribute__((ext_vector_type(8)));
typedef __bf16 bf16x8 __attribute__((ext_vector_type(8)));
typedef float f32x4 __attribute__((ext_vector_type(4)));
typedef float f32x2 __attribute__((ext_vector_type(2)));
typedef _Float16 half2v __attribute__((ext_vector_type(2)));

#if defined(__has_builtin)
#if __has_builtin(__builtin_amdgcn_cvt_f32_fp8)
#define HAS_CVTFP8 1
#endif
#if __has_builtin(__builtin_amdgcn_cvt_pk_f32_fp8)
#define HAS_PKFP8 1
#endif
#if __has_builtin(__builtin_amdgcn_cvt_pk_fp8_f32)
#define HAS_PKFP8E 1
#endif
#endif

__device__ inline unsigned short f2bf(float f) {
  unsigned u = __float_as_uint(f);
  u += 0x7FFFu + ((u >> 16) & 1u);
  return (unsigned short)(u >> 16);
}
__device__ inline float bf2f(unsigned short h) {
  return __uint_as_float(((unsigned)h) << 16);
}

// OCP e4m3 encode (RNE, clamp to +-448, denormals handled) — software fallback
__device__ inline unsigned char f2fp8(float f) {
  const float af = fabsf(f);
  const unsigned s = (f < 0.f) ? 0x80u : 0u;
  if (af >= 448.f) return (unsigned char)(s | 0x7E);
  if (af < 0.015625f) {
    int q = (int)(af * 512.f + 0.5f);
    return (unsigned char)(s | q);
  }
  unsigned u = __float_as_uint(af);
  unsigned m = u & 0x7fffffu;
  unsigned e = u >> 23;
  unsigned r = m + 0x7ffffu + ((m >> 20) & 1u);
  if (r >> 23) { e += 1; r = 0; }
  unsigned em = ((e - 120u) << 3) | ((r >> 20) & 7u);
  if (em > 0x7Eu) em = 0x7Eu;
  return (unsigned char)(s | em);
}

// packed fp8 encode: 2 f32 -> u32 with bytes[0]=fp8(a), bytes[1]=fp8(b)
__device__ inline unsigned pk8e(float a, float b) {
#ifdef HAS_PKFP8E
  return (unsigned)__builtin_amdgcn_cvt_pk_fp8_f32(a, b, 0, false);
#else
  return (unsigned)f2fp8(a) | ((unsigned)f2fp8(b) << 8);
#endif
}

// OCP e4m3 decode, byte SEL of a dword (compile-time constant)
template <int SEL>
__device__ inline float fp8tof(unsigned v) {
#ifdef HAS_CVTFP8
  return __builtin_amdgcn_cvt_f32_fp8(v, SEL);
#else
  unsigned b = (v >> (SEL * 8)) & 0xffu;
  unsigned em = b & 0x7fu;
  float n = __uint_as_float((em << 20) + 0x3C000000u);
  float dn = (float)em * 0.001953125f;
  float r = (em < 8u) ? dn : n;
  return (b & 0x80u) ? -r : r;
#endif
}

// packed fp8 pair decode: bytes [1:0] (hi=false) or [3:2] (hi=true)
template <bool HI>
__device__ inline f32x2 pk8(unsigned w) {
#ifdef HAS_PKFP8
  return __builtin_amdgcn_cvt_pk_f32_fp8((int)w, HI);
#else
  f32x2 r;
  if (HI) { r[0] = fp8tof<2>(w); r[1] = fp8tof<3>(w); }
  else    { r[0] = fp8tof<0>(w); r[1] = fp8tof<1>(w); }
  return r;
#endif
}

__device__ inline void gload16(const void* g, void* l) {
  __builtin_amdgcn_global_load_lds((const __attribute__((address_space(1))) void*)g,
                                   (__attribute__((address_space(3))) void*)l, 16, 0, 0);
}

// ---------------- CSR build (rank-based: one atomic pass) ----------------

__global__ void hist_kernel(const int* __restrict__ dst, int* __restrict__ deg,
                            int* __restrict__ rank) {
  int i = blockIdx.x * blockDim.x + threadIdx.x;
  int stride = gridDim.x * blockDim.x;
  for (; i < Ee; i += stride) rank[i] = atomicAdd(&deg[dst[i]], 1);
}

__global__ __launch_bounds__(1024) void scan1_kernel(const int* __restrict__ deg,
                                                     int* __restrict__ off,
                                                     int* __restrict__ bsum) {
  __shared__ int wsum[16];
  int tid = threadIdx.x, lane = tid & 63, w = tid >> 6;
  int i = blockIdx.x * 1024 + tid;
  int v = (i < Nn) ? deg[i] : 0;
  int x = v;
#pragma unroll
  for (int o = 1; o < 64; o <<= 1) {
    int t = __shfl_up(x, o);
    if (lane >= o) x += t;
  }
  if (lane == 63) wsum[w] = x;
  __syncthreads();
  if (w == 0 && lane < 16) {
    int y = wsum[lane];
#pragma unroll
    for (int o = 1; o < 16; o <<= 1) {
      int t = __shfl_up(y, o);
      if (lane >= o) y += t;
    }
    wsum[lane] = y;
  }
  __syncthreads();
  int incl = x + (w ? wsum[w - 1] : 0);
  if (i < Nn) off[i] = incl - v;
  if (tid == 1023) bsum[blockIdx.x] = incl;
}

__global__ void scan2_kernel(const int* __restrict__ bsum, int* __restrict__ boff,
                             int* __restrict__ offN) {
  int lane = threadIdx.x;
  int v = (lane < SCANB) ? bsum[lane] : 0;
  int x = v;
#pragma unroll
  for (int o = 1; o < 64; o <<= 1) {
    int t = __shfl_up(x, o);
    if (lane >= o) x += t;
  }
  if (lane < SCANB) boff[lane] = x - v;
  if (lane == 63) *offN = x;
}

__global__ void scan3_kernel(int* __restrict__ off, const int* __restrict__ boff) {
  int i = blockIdx.x * 256 + threadIdx.x;
  if (i < Nn) off[i] += boff[i >> 10];
}

__global__ void scatter_kernel(const int* __restrict__ src, const int* __restrict__ dst,
                               const int* __restrict__ off, const int* __restrict__ rank,
                               int* __restrict__ ssrc) {
  int i = blockIdx.x * blockDim.x + threadIdx.x;
  int stride = gridDim.x * blockDim.x;
  for (; i < Ee; i += stride) {
    ssrc[off[dst[i]] + rank[i]] = src[i];
  }
}

// ---------------- conversions ----------------

__global__ void round_kernel(const float* __restrict__ in, unsigned short* __restrict__ out,
                             int M, int K) {
  const int kg4 = K >> 2;
  int i = blockIdx.x * blockDim.x + threadIdx.x;
  const int total = M * kg4;
  const int stride = gridDim.x * blockDim.x;
  for (; i < total; i += stride) {
    const int row = i / kg4, kg = i - row * kg4;
    const float4 v = *(const float4*)(in + (size_t)row * K + kg * 4);
    ushort4 h;
    h.x = f2bf(v.x); h.y = f2bf(v.y); h.z = f2bf(v.z); h.w = f2bf(v.w);
    *(ushort4*)(out + (size_t)row * K + kg * 4) = h;
  }
}

// 4x W [K][256] fp32 -> B [1024][K] bf16 hi-only, transposed; row n = z*256+c
__global__ void convw_kernel(const float* __restrict__ W0, const float* __restrict__ W1,
                             const float* __restrict__ W2, const float* __restrict__ W3,
                             unsigned short* __restrict__ B, int K) {
  int i = blockIdx.x * blockDim.x + threadIdx.x;
  const int total = 1024 * K;
  const int stride = gridDim.x * blockDim.x;
  for (; i < total; i += stride) {
    const int n = i & 1023;
    const int k = i >> 10;
    const int z = n >> 8, c = n & 255;
    const float* W = z == 0 ? W0 : z == 1 ? W1 : z == 2 ? W2 : W3;
    B[(size_t)n * K + k] = f2bf(W[(size_t)k * Dd + c]);
  }
}

// ---------------- 1-term bf16 MFMA GEMM (128x128 tile) ----------------
// C = A_bf16 @ B_hi + bias.  A [M][K] bf16, B [1024][K] bf16.
// z=(i2&7)>>1: 0 -> q fp16 [M][256] direct store; 1 -> K fp8 kv[row*512+c] via
// LDS restage; 2 -> V fp8 kv[row*512+256+c] via LDS restage; 3 -> s fp16 direct.

__global__ __launch_bounds__(256)
void gemm_mfma(const unsigned short* __restrict__ A2, int M, int K,
               const unsigned short* __restrict__ B,
               const float* __restrict__ b0, const float* __restrict__ b1,
               const float* __restrict__ b2, const float* __restrict__ b3,
               _Float16* __restrict__ qout, unsigned char* __restrict__ kvout,
               _Float16* __restrict__ sout) {
  __shared__ __align__(16) char smem[32768];
  unsigned short* As = (unsigned short*)smem;
  unsigned short* Bs = (unsigned short*)(smem + 16384);
  const int tid = threadIdx.x;
  const int lane = tid & 63, w = tid >> 6;
  const int wr = w >> 1, wc = w & 1;
  const int p = blockIdx.x;
  const int xcd = p & 7;
  const int i2 = p >> 3;
  const int bm = (xcd * 49 + (i2 >> 3)) * 128;
  const int zblk = (i2 & 7) >> 1;
  const int colbase = (i2 & 1) * 128;          // block's 128 cols within its z
  const int lda = K, ldb = K;
  const int nsteps = K >> 6;
  const int srow = lane >> 3, sslot = lane & 7;
  const int fr = lane & 15, fq = lane >> 4;

  f32x4 acc[4][4] = {};

  for (int s = 0; s < nsteps; ++s) {
    const int kk = s << 6;
    __syncthreads();
#pragma unroll
    for (int h = 0; h < 4; ++h) {
      const int q = h * 4 + w;
      const int r = q * 8 + srow;
      const int g = sslot ^ (r & 7);
      int ga = bm + r; if (ga > M - 1) ga = M - 1;
      gload16(A2 + (size_t)ga * lda + kk + g * 8, (char*)As + q * 1024);
      const int gb = (zblk * 256 + colbase) + r;   // B row = z*256 + c
      gload16(B + (size_t)gb * ldb + kk + g * 8, (char*)Bs + q * 1024);
    }
    __syncthreads();
    short8 av[2][4], bv[2][4];
#pragma unroll
    for (int kh = 0; kh < 2; ++kh)
#pragma unroll
      for (int i = 0; i < 4; ++i) {
        const int ra = wr * 64 + i * 16 + fr;
        av[kh][i] = *(const short8*)((const char*)As + ra * 128 + (((kh * 4 + fq) ^ (ra & 7)) << 4));
        const int rb = wc * 64 + i * 16 + fr;
        bv[kh][i] = *(const short8*)((const char*)Bs + rb * 128 + (((kh * 4 + fq) ^ (rb & 7)) << 4));
      }
#pragma unroll
    for (int kh = 0; kh < 2; ++kh)
#pragma unroll
      for (int mi = 0; mi < 4; ++mi)
#pragma unroll
        for (int ni = 0; ni < 4; ++ni)
          acc[mi][ni] = __builtin_amdgcn_mfma_f32_16x16x32_bf16(
              __builtin_bit_cast(bf16x8, av[kh][mi]),
              __builtin_bit_cast(bf16x8, bv[kh][ni]), acc[mi][ni], 0, 0, 0);
  }

  // ---- bias folded into acc (per-thread col fixed per ni) ----
  {
    const float* bp = zblk == 0 ? b0 : zblk == 1 ? b1 : zblk == 2 ? b2 : b3;
#pragma unroll
    for (int ni = 0; ni < 4; ++ni) {
      const float bias = bp[colbase + wc * 64 + ni * 16 + fr];
#pragma unroll
      for (int mi = 0; mi < 4; ++mi)
#pragma unroll
        for (int j = 0; j < 4; ++j) acc[mi][ni][j] += bias;
    }
  }

  if (zblk == 0 || zblk == 3) {
    // ---- fp16 direct stores (r5-style), no LDS, no extra barriers ----
    _Float16* out = (zblk == 0) ? qout : sout;
#pragma unroll
    for (int mi = 0; mi < 4; ++mi) {
      const int grow0 = bm + wr * 64 + mi * 16 + fq * 4;
#pragma unroll
      for (int ni = 0; ni < 4; ++ni) {
        const int c = colbase + wc * 64 + ni * 16 + fr;
#pragma unroll
        for (int j = 0; j < 4; ++j) {
          const int grow = grow0 + j;
          if (grow < M) out[(size_t)grow * Dd + c] = (_Float16)acc[mi][ni][j];
        }
      }
    }
  } else {
    // ---- fp8: restage into first 16KB of LDS (XOR swizzle), coalesced flush ----
    unsigned char* S8 = (unsigned char*)smem;
    __syncthreads();   // K-loop LDS reads done before overwrite
#pragma unroll
    for (int mi = 0; mi < 4; ++mi)
#pragma unroll
      for (int ni = 0; ni < 4; ++ni) {
        const int col = wc * 64 + ni * 16 + fr;
        const int row0 = wr * 64 + mi * 16 + fq * 4;
        const unsigned pk01 = pk8e(acc[mi][ni][0], acc[mi][ni][1]);
        const unsigned pk23 = pk8e(acc[mi][ni][2], acc[mi][ni][3]);
        S8[(row0 + 0) * 128 + (col ^ (((row0 + 0) & 7) << 4))] = (unsigned char)pk01;
        S8[(row0 + 1) * 128 + (col ^ (((row0 + 1) & 7) << 4))] = (unsigned char)(pk01 >> 8);
        S8[(row0 + 2) * 128 + (col ^ (((row0 + 2) & 7) << 4))] = (unsigned char)pk23;
        S8[(row0 + 3) * 128 + (col ^ (((row0 + 3) & 7) << 4))] = (unsigned char)(pk23 >> 8);
      }
    __syncthreads();
    const int row = tid >> 1, half = tid & 1;
    const int grow = bm + row;
    if (grow < M) {
      const int sh = (row & 7) << 4;
      uint4* dstp = (uint4*)(kvout + (size_t)grow * 512 + (zblk == 2 ? 256 : 0) +
                             colbase + half * 64);
#pragma unroll
      for (int k = 0; k < 4; ++k)
        dstp[k] = *(const uint4*)(smem + row * 128 + ((half * 64 + k * 16) ^ sh));
    }
  }
}

// ---------------- per-node attention: half-wave edge pairing ----------------
// One wave per dst node. Lanes 0-31 process even edges, 32-63 odd edges.
// Channel layout: lane hl (=lane&31) owns channels 8hl..8hl+7.
// Heads (H=2, C=128): head0 = lanes 0-15 of each half, head1 = lanes 16-31.
// Score reduce = 4 shfl steps over 16 lanes. Final cross-half softmax merge.
// q fp16 [Nn][256]; kv row 512B: K fp8 [0,256), V fp8 [256,512); s fp16; out bf16.

__global__ __launch_bounds__(256)
void attn_kernel(const _Float16* __restrict__ qbuf, const unsigned char* __restrict__ kvb,
                 const _Float16* __restrict__ sbuf, const int* __restrict__ off,
                 const int* __restrict__ ssrc, unsigned short* __restrict__ hbout) {
  const int gw = (int)((blockIdx.x * 256 + threadIdx.x) >> 6);
  if (gw >= Nn) return;
  const int lane = threadIdx.x & 63;
  const int half = lane >> 5;
  const int hl = lane & 31;
  const float scale = 0.08838834764831845f;

  // q: 8 fp16 channels -> float
  const uint4 qv = *(const uint4*)((const char*)qbuf + (size_t)gw * 512 + hl * 16);
  float qf[8];
  {
    const half2v h0 = __builtin_bit_cast(half2v, qv.x);
    const half2v h1 = __builtin_bit_cast(half2v, qv.y);
    const half2v h2 = __builtin_bit_cast(half2v, qv.z);
    const half2v h3 = __builtin_bit_cast(half2v, qv.w);
    qf[0] = h0[0]; qf[1] = h0[1]; qf[2] = h1[0]; qf[3] = h1[1];
    qf[4] = h2[0]; qf[5] = h2[1]; qf[6] = h3[0]; qf[7] = h3[1];
  }

  const int e0 = off[gw], e1 = off[gw + 1];
  float m = -3.4e38f, d = 0.f;
  float acc[8] = {};

  for (int e = e0; e < e1; e += 8) {
    int sx[4];
    float vald[4];
#pragma unroll
    for (int t = 0; t < 4; ++t) {
      const int ee = e + 2 * t + half;
      vald[t] = (ee < e1) ? 1.f : 0.f;
      sx[t] = ssrc[ee < e1 ? ee : e1 - 1];
    }
    uint2 ku[4], vu[4];
#pragma unroll
    for (int t = 0; t < 4; ++t) {
      const unsigned char* row = kvb + (size_t)sx[t] * 512;
      ku[t] = *(const uint2*)(row + hl * 8);
      vu[t] = *(const uint2*)(row + 256 + hl * 8);
    }
    float p[4];
#pragma unroll
    for (int t = 0; t < 4; ++t) {
      const f32x2 k01 = pk8<false>(ku[t].x), k23 = pk8<true>(ku[t].x);
      const f32x2 k45 = pk8<false>(ku[t].y), k67 = pk8<true>(ku[t].y);
      float pp = qf[0] * k01[0];
      pp = fmaf(qf[1], k01[1], pp);
      pp = fmaf(qf[2], k23[0], pp);
      pp = fmaf(qf[3], k23[1], pp);
      pp = fmaf(qf[4], k45[0], pp);
      pp = fmaf(qf[5], k45[1], pp);
      pp = fmaf(qf[6], k67[0], pp);
      pp = fmaf(qf[7], k67[1], pp);
      p[t] = pp;
    }
#pragma unroll
    for (int o = 8; o >= 1; o >>= 1)
#pragma unroll
      for (int t = 0; t < 4; ++t) p[t] += __shfl_xor(p[t], o);
    float sct[4];
#pragma unroll
    for (int t = 0; t < 4; ++t)
      sct[t] = vald[t] ? p[t] * scale : -3.4e38f;
    float mx = m;
#pragma unroll
    for (int t = 0; t < 4; ++t) mx = fmaxf(mx, sct[t]);
    const float f = __expf(m - mx);
    float wsum = 0.f;
    float vacc[8] = {};
#pragma unroll
    for (int t = 0; t < 4; ++t) {
      const float wt = __expf(sct[t] - mx) * vald[t];
      wsum += wt;
      const f32x2 v01 = pk8<false>(vu[t].x), v23 = pk8<true>(vu[t].x);
      const f32x2 v45 = pk8<false>(vu[t].y), v67 = pk8<true>(vu[t].y);
      vacc[0] = fmaf(wt, v01[0], vacc[0]);
      vacc[1] = fmaf(wt, v01[1], vacc[1]);
      vacc[2] = fmaf(wt, v23[0], vacc[2]);
      vacc[3] = fmaf(wt, v23[1], vacc[3]);
      vacc[4] = fmaf(wt, v45[0], vacc[4]);
      vacc[5] = fmaf(wt, v45[1], vacc[5]);
      vacc[6] = fmaf(wt, v67[0], vacc[6]);
      vacc[7] = fmaf(wt, v67[1], vacc[7]);
    }
    d = d * f + wsum;
#pragma unroll
    for (int j = 0; j < 8; ++j) acc[j] = fmaf(acc[j], f, vacc[j]);
    m = mx;
  }

  // cross-half online-softmax merge (lane l <-> l+32, same channels & head)
  {
    const float m2 = __shfl_xor(m, 32);
    const float d2 = __shfl_xor(d, 32);
    float acc2[8];
#pragma unroll
    for (int j = 0; j < 8; ++j) acc2[j] = __shfl_xor(acc[j], 32);
    const float M = fmaxf(m, m2);
    const float f1 = __expf(m - M);
    const float f2 = __expf(m2 - M);
    d = d * f1 + d2 * f2;
#pragma unroll
    for (int j = 0; j < 8; ++j) acc[j] = acc[j] * f1 + acc2[j] * f2;
  }

  if (half == 0) {
    const float inv = 1.f / (d + 1e-16f);
    const uint4 sv = *(const uint4*)((const char*)sbuf + (size_t)gw * 512 + hl * 16);
    const half2v s0 = __builtin_bit_cast(half2v, sv.x);
    const half2v s1 = __builtin_bit_cast(half2v, sv.y);
    const half2v s2 = __builtin_bit_cast(half2v, sv.z);
    const half2v s3 = __builtin_bit_cast(half2v, sv.w);
    const float sf[8] = {(float)s0[0], (float)s0[1], (float)s1[0], (float)s1[1],
                         (float)s2[0], (float)s2[1], (float)s3[0], (float)s3[1]};
    unsigned short ob[8];
#pragma unroll
    for (int j = 0; j < 8; ++j)
      ob[j] = f2bf(fmaxf(fmaf(acc[j], inv, sf[j]), 0.f));
    *(uint4*)((char*)hbout + (size_t)gw * 512 + hl * 16) = *(const uint4*)ob;
  }
}

// ---------------- pooling (bf16 input) + fc ----------------

__global__ __launch_bounds__(256)
void pool_kernel(const unsigned short* __restrict__ h, const int* __restrict__ batch,
                 float* __restrict__ pooled) {
  int c = threadIdx.x;
  int n0 = blockIdx.x * 128;
  int n1 = min(n0 + 128, Nn);
  int curg = batch[n0];
  float mx = 0.f;
  for (int n = n0; n < n1; ++n) {
    int g = batch[n];
    if (g != curg) {
      atomicMax((int*)(pooled + curg * Dd + c), __float_as_int(mx));
      mx = 0.f;
      curg = g;
    }
    mx = fmaxf(mx, bf2f(h[(size_t)n * Dd + c]));
  }
  atomicMax((int*)(pooled + curg * Dd + c), __float_as_int(mx));
}

__global__ __launch_bounds__(512)
void fc_kernel(const float* __restrict__ pooled,
               const float* __restrict__ wf1, const float* __restrict__ bf1,
               const float* __restrict__ wf2, const float* __restrict__ bf2,
               float* __restrict__ outp) {
  __shared__ float t[Gg][64];
  int tid = threadIdx.x;
  int g = tid >> 6, j = tid & 63;
  float acc = bf1[j];
  for (int c = 0; c < Dd; ++c) acc = fmaf(pooled[g * Dd + c], wf1[c * 64 + j], acc);
  t[g][j] = acc;
  __syncthreads();
  if (tid < Gg * 4) {
    int gg = tid >> 2, cc = tid & 3;
    float a2 = bf2[cc];
    for (int j2 = 0; j2 < 64; ++j2) a2 = fmaf(t[gg][j2], wf2[j2 * 4 + cc], a2);
    outp[gg * 4 + cc] = a2;
  }
}

// ---------------- host ----------------

extern "C" void kernel_launch(void* const* d_in, const int* in_sizes, int n_in,
                              void* d_out, int out_size, void* d_ws, size_t ws_size,
                              hipStream_t stream) {
  const float* x   = (const float*)d_in[0];
  const int* ei    = (const int*)d_in[1];
  const int* srcE  = ei;
  const int* dstE  = ei + Ee;
  const int* batch = (const int*)d_in[2];
  const float* wq1 = (const float*)d_in[3];  const float* bq1 = (const float*)d_in[4];
  const float* wk1 = (const float*)d_in[5];  const float* bk1 = (const float*)d_in[6];
  const float* wv1 = (const float*)d_in[7];  const float* bv1 = (const float*)d_in[8];
  const float* ws1 = (const float*)d_in[9];  const float* bs1 = (const float*)d_in[10];
  const float* wq2 = (const float*)d_in[11]; const float* bq2 = (const float*)d_in[12];
  const float* wk2 = (const float*)d_in[13]; const float* bk2 = (const float*)d_in[14];
  const float* wv2 = (const float*)d_in[15]; const float* bv2 = (const float*)d_in[16];
  const float* ws2 = (const float*)d_in[17]; const float* bs2 = (const float*)d_in[18];
  const float* wf1 = (const float*)d_in[19]; const float* bf1 = (const float*)d_in[20];
  const float* wf2 = (const float*)d_in[21]; const float* bf2 = (const float*)d_in[22];
  float* outp = (float*)d_out;
  char* ws = (char*)d_ws;

  auto al256 = [](size_t v) { return (v + 255) & ~(size_t)255; };
  size_t o_deg  = 0;
  size_t o_pool = o_deg + (size_t)Nn * 4;
  size_t zbytes = o_pool + (size_t)Gg * Dd * 4;
  size_t o_off  = al256(zbytes);
  size_t o_ssrc = al256(o_off + (size_t)(Nn + 1) * 4);
  size_t o_rank = al256(o_ssrc + (size_t)Ee * 4);
  size_t o_q    = al256(o_rank + (size_t)Ee * 4);                 // fp16 [Nn][256]
  size_t o_kv   = al256(o_q + (size_t)Nn * Dd * 2);               // 512B rows [Nn]
  size_t o_s    = al256(o_kv + (size_t)Nn * 512);                 // fp16 [Nn][256]
  size_t o_b1   = al256(o_s + (size_t)Nn * Dd * 2);               // bf16 [1024][512]
  size_t o_b2   = al256(o_b1 + (size_t)1024 * Ff * 2);            // bf16 [1024][256]
  size_t o_a    = al256(o_b2 + (size_t)1024 * Dd * 2);            // bf16 [Nn][512] x / h overlay
  size_t o_bsum = al256(o_a + (size_t)Nn * Ff * 2);
  size_t o_boff = al256(o_bsum + (size_t)SCANB * 4);
  size_t total  = o_boff + (size_t)SCANB * 4;
  if (ws_size < total) {
    fprintf(stderr, "kernel_launch: ws too small: %zu < %zu\n", ws_size, total);
    return;
  }

  int*   deg    = (int*)(ws + o_deg);
  float* pooled = (float*)(ws + o_pool);
  int*   off    = (int*)(ws + o_off);
  int*   ssrc   = (int*)(ws + o_ssrc);
  int*   rank   = (int*)(ws + o_rank);
  _Float16* qb  = (_Float16*)(ws + o_q);
  unsigned char* kvb = (unsigned char*)(ws + o_kv);
  _Float16* sb  = (_Float16*)(ws + o_s);
  unsigned short* b1 = (unsigned short*)(ws + o_b1);
  unsigned short* b2 = (unsigned short*)(ws + o_b2);
  unsigned short* a2  = (unsigned short*)(ws + o_a);    // [Nn][512] bf16 (x)
  unsigned short* hb  = (unsigned short*)(ws + o_a);    // [Nn][256] bf16 h (overlays a2)
  int* bsum     = (int*)(ws + o_bsum);
  int* boff     = (int*)(ws + o_boff);

  (void)hipMemsetAsync(ws, 0, zbytes, stream);
  hist_kernel<<<1024, 256, 0, stream>>>(dstE, deg, rank);
  scan1_kernel<<<SCANB, 1024, 0, stream>>>(deg, off, bsum);
  scan2_kernel<<<1, 64, 0, stream>>>(bsum, boff, off + Nn);
  scan3_kernel<<<(Nn + 255) / 256, 256, 0, stream>>>(off, boff);
  scatter_kernel<<<1024, 256, 0, stream>>>(srcE, dstE, off, rank, ssrc);

  convw_kernel<<<1024, 256, 0, stream>>>(wq1, wk1, wv1, ws1, b1, Ff);
  convw_kernel<<<1024, 256, 0, stream>>>(wq2, wk2, wv2, ws2, b2, Dd);
  round_kernel<<<4096, 256, 0, stream>>>(x, a2, Nn, Ff);

  gemm_mfma<<<3136, 256, 0, stream>>>(a2, Nn, Ff, b1, bq1, bk1, bv1, bs1, qb, kvb, sb);
  attn_kernel<<<(Nn + 3) / 4, 256, 0, stream>>>(qb, kvb, sb, off, ssrc, hb);
  gemm_mfma<<<3136, 256, 0, stream>>>(hb, Nn, Dd, b2, bq2, bk2, bv2, bs2, qb, kvb, sb);
  attn_kernel<<<(Nn + 3) / 4, 256, 0, stream>>>(qb, kvb, sb, off, ssrc, hb);

  pool_kernel<<<(Nn + 127) / 128, 256, 0, stream>>>(hb, batch, pooled);
  fc_kernel<<<1, 512, 0, stream>>>(pooled, wf1, bf1, wf2, bf2, outp);
}